// Round 19
// baseline (719.574 us; speedup 1.0000x reference)
//
#include <hip/hip_runtime.h>
#include <hip/hip_bf16.h>
#include <stdint.h>

typedef __attribute__((ext_vector_type(8))) short bf16x8;
typedef __attribute__((ext_vector_type(4))) float f32x4;
typedef __attribute__((ext_vector_type(4))) float float4v;

__device__ __forceinline__ uint16_t bfc(float x){
    __hip_bfloat16 h = __float2bfloat16(x);
    return __builtin_bit_cast(uint16_t, h);
}
__device__ __forceinline__ uint32_t pk2(float a, float b){
    return (uint32_t)bfc(a) | ((uint32_t)bfc(b) << 16);
}
__device__ __forceinline__ float fsigmoid(float x){ return 1.0f / (1.0f + __expf(-x)); }
__device__ __forceinline__ float fsilu(float x){ return x * fsigmoid(x); }

__device__ __forceinline__ bf16x8 pack8(float4v lo, float4v hi){
    bf16x8 r;
    r[0]=(short)bfc(lo[0]); r[1]=(short)bfc(lo[1]);
    r[2]=(short)bfc(lo[2]); r[3]=(short)bfc(lo[3]);
    r[4]=(short)bfc(hi[0]); r[5]=(short)bfc(hi[1]);
    r[6]=(short)bfc(hi[2]); r[7]=(short)bfc(hi[3]);
    return r;
}

// ---------------- weight prep (R2-validated fragpos map) ----------------
#define SZ_BE1 4096
#define SZ_128 16384
#define SZ_D1  32768
#define SZ_D2  65536
#define SZ_F1  98304
#define OFF_BE1 0
#define OFF_BE2 (OFF_BE1 + SZ_BE1)    // 4096
#define OFF_BE3 (OFF_BE2 + SZ_128)    // 20480
#define OFF_D1  (OFF_BE3 + SZ_128)    // 36864
#define OFF_D2  (OFF_D1 + SZ_D1)      // 69632
#define OFF_F1  (OFF_D2 + SZ_D2)      // 135168
#define OFF_F2  (OFF_F1 + SZ_F1)      // 233472
#define WS_ELEMS (OFF_F2 + SZ_D2)     // 299008 bf16 elems = 598016 B

__device__ __forceinline__ int fragpos(int k, int c, int OUT){
    int kt = k >> 5, ct = c >> 4;
    int fid = kt * (OUT >> 4) + ct;
    int ln = ((k & 31) >> 3) * 16 + (c & 15);
    return fid * 512 + ln * 8 + (k & 7);
}

__global__ void __launch_bounds__(256)
prep_w(const float* __restrict__ Wbe1, const float* __restrict__ Wbe2,
       const float* __restrict__ Wbe3, const float* __restrict__ Wd1,
       const float* __restrict__ Wd2,  const float* __restrict__ Wf1,
       const float* __restrict__ Wf2,  uint16_t* __restrict__ ws){
    int t = blockIdx.x * 256 + threadIdx.x;
    if (t >= WS_ELEMS) return;
    if (t < OFF_BE2) {                        // be1: K padded 16 -> 32
        int u = t;            int k = u >> 7, c = u & 127;
        float v = (k < 16) ? Wbe1[k * 128 + c] : 0.0f;
        ws[OFF_BE1 + fragpos(k, c, 128)] = bfc(v);
    } else if (t < OFF_BE3) {
        int u = t - OFF_BE2;  int k = u >> 7, c = u & 127;
        ws[OFF_BE2 + fragpos(k, c, 128)] = bfc(Wbe2[u]);
    } else if (t < OFF_D1) {
        int u = t - OFF_BE3;  int k = u >> 7, c = u & 127;
        ws[OFF_BE3 + fragpos(k, c, 128)] = bfc(Wbe3[u]);
    } else if (t < OFF_D2) {
        int u = t - OFF_D1;   int k = u >> 8, c = u & 255;
        ws[OFF_D1 + fragpos(k, c, 256)] = bfc(Wd1[u]);
    } else if (t < OFF_F1) {
        int u = t - OFF_D2;   int k = u >> 8, c = u & 255;
        ws[OFF_D2 + fragpos(k, c, 256)] = bfc(Wd2[u]);
    } else if (t < OFF_F2) {                  // f1 rows 0..383 only
        int u = t - OFF_F1;   int k = u >> 8, c = u & 255;
        ws[OFF_F1 + fragpos(k, c, 256)] = bfc(Wf1[u]);
    } else {
        int u = t - OFF_F2;   int k = u >> 8, c = u & 255;
        ws[OFF_F2 + fragpos(k, c, 256)] = bfc(Wf2[u]);
    }
}

__global__ void __launch_bounds__(256)
prep_n(const float* __restrict__ src, uint16_t* __restrict__ dst, int n){
    int t = blockIdx.x * 256 + threadIdx.x;
    if (t < n) dst[t] = bfc(src[t]);
}

// ---------------- async global->LDS helper ----------------
typedef const __attribute__((address_space(1))) void gas_void;
typedef __attribute__((address_space(3))) void las_void;
__device__ __forceinline__ void g2l16(const void* g, void* l){
    __builtin_amdgcn_global_load_lds((gas_void*)g, (las_void*)l, 16, 0, 0);
}

// ==================== TIER 1: per-layer kernels (activations in ws) ====================
// R16 structure + FULL UNROLL of kt loops (R10 mechanism: compile-time wbuf/ldf
// offsets, ~half the addressing VALU; barriers fence each step so no hoisting).

// ---- k_be: BE1+BE2+BE3 fused, 128 edges/block, e3 -> e3buf (bf16 linear) ----
__global__ void __launch_bounds__(512)
k_be(const float* __restrict__ edge_attr,
     const float* __restrict__ b_be1, const float* __restrict__ g_be1, const float* __restrict__ bb_be1,
     const float* __restrict__ b_be2, const float* __restrict__ g_be2, const float* __restrict__ bb_be2,
     const float* __restrict__ b_be3, const float* __restrict__ g_be3, const float* __restrict__ bb_be3,
     const uint16_t* __restrict__ ws, uint16_t* __restrict__ e3buf, int E)
{
    __shared__ char lds[49152];   // bufE 32KB + wb0/wb1 8KB each
    const int t = threadIdx.x, wave = t >> 6, lane = t & 63;
    const int li = lane & 15, lg = lane >> 4;
    const int e0b = blockIdx.x * 128;
    char* bufE = lds;
    uint16_t* wb0 = (uint16_t*)(lds + 32768);
    uint16_t* wb1 = (uint16_t*)(lds + 40960);
    const uint8_t* wsb = (const uint8_t*)ws;

    int cur = 0;
    auto stage8 = [&](int elemoff){
        g2l16(wsb + (size_t)elemoff * 2 + t * 16, (uint8_t*)(cur ? wb0 : wb1) + t * 16);
    };
    auto stepend = [&](){ __syncthreads(); cur ^= 1; };
    auto curb = [&]() -> const uint16_t* { return cur ? wb1 : wb0; };

    f32x4 acc[8];
    auto ldf = [&](int fid) -> bf16x8 { return *(const bf16x8*)(curb() + fid * 512 + lane * 8); };
    auto eb_read = [&](int row, int kt) -> bf16x8 {
        int off = row * 256 + (kt * 32 + lg * 8) * 2;
        return *(const bf16x8*)(bufE + (off ^ ((row & 7) << 4)));
    };
    auto initBE = [&](const float* b){
        #pragma unroll
        for (int ct = 0; ct < 8; ++ct){ float bv = b[li + 16*ct]; f32x4 iv = {bv,bv,bv,bv}; acc[ct] = iv; }
    };
    auto grpBE = [&](bf16x8 a0){
        #pragma unroll
        for (int ct = 0; ct < 8; ++ct)
            acc[ct] = __builtin_amdgcn_mfma_f32_16x16x32_bf16(a0, ldf(ct), acc[ct], 0, 0, 0);
    };
    auto lnstoreBE = [&](const float* g, const float* bb){
        #pragma unroll
        for (int r = 0; r < 4; ++r){
            float s = 0.f, q = 0.f;
            #pragma unroll
            for (int ct = 0; ct < 8; ++ct){ float v = acc[ct][r]; s += v; q += v*v; }
            s += __shfl_xor(s, 1); q += __shfl_xor(q, 1);
            s += __shfl_xor(s, 2); q += __shfl_xor(q, 2);
            s += __shfl_xor(s, 4); q += __shfl_xor(q, 4);
            s += __shfl_xor(s, 8); q += __shfl_xor(q, 8);
            float mu = s * 0.0078125f;
            float var = q * 0.0078125f - mu * mu;
            float rs = rsqrtf(var + 1e-5f);
            int row = wave * 16 + lg * 4 + r;
            int rswz = (row & 7) << 4;
            #pragma unroll
            for (int ct = 0; ct < 8; ++ct){
                int col = li + 16 * ct;
                float v = (acc[ct][r] - mu) * rs * g[col] + bb[col];
                int off = row * 256 + col * 2;
                *(uint16_t*)(bufE + (off ^ rswz)) = bfc(fsilu(v));
            }
        }
    };

    // prologue: BE1 chunk (8KB) -> wb0
    g2l16(wsb + t * 16, (uint8_t*)wb0 + t * 16);
    __syncthreads();

    // BE1 (K=16 pad 32)
    {
        stage8(OFF_BE2);
        initBE(b_be1);
        bf16x8 aE = {0,0,0,0,0,0,0,0};
        if (lg < 2){
            int ea = e0b + wave * 16 + li; if (ea >= E) ea = E - 1;
            const float* pa = edge_attr + (size_t)ea * 16 + lg * 8;
            aE = pack8(*(const float4v*)pa, *(const float4v*)(pa + 4));
        }
        grpBE(aE);
        lnstoreBE(g_be1, bb_be1);
        stepend();
    }
    // BE2
    initBE(b_be2);
    #pragma unroll
    for (int kt = 0; kt < 4; ++kt){
        stage8(kt < 3 ? OFF_BE2 + (kt + 1) * 4096 : OFF_BE3);
        grpBE(eb_read(wave * 16 + li, kt));
        if (kt == 3) lnstoreBE(g_be2, bb_be2);
        stepend();
    }
    // BE3
    initBE(b_be3);
    #pragma unroll
    for (int kt = 0; kt < 4; ++kt){
        if (kt < 3) stage8(OFF_BE3 + (kt + 1) * 4096);
        grpBE(eb_read(wave * 16 + li, kt));
        if (kt == 3) lnstoreBE(g_be3, bb_be3);
        stepend();                               // last barrier makes e3 visible for copy
    }
    // copy bufE -> e3buf (unswizzle, coalesced 16B)
    #pragma unroll
    for (int i = 0; i < 4; ++i){
        int b = t * 16 + i * 8192;
        int row = b >> 8;
        uint4 v = *(const uint4*)(bufE + (b ^ ((row & 7) << 4)));
        *(uint4*)((uint8_t*)e3buf + (size_t)e0b * 256 + b) = v;
    }
}

// ---- k_d1: 128 -> 256, A from dual_emb f32, out hd1 -> hbuf ----
__global__ void __launch_bounds__(512)
k_d1(const float* __restrict__ dual_emb, const float* __restrict__ b_d1,
     const uint16_t* __restrict__ ws, uint16_t* __restrict__ hbuf, int E)
{
    __shared__ char lds[32768];
    const int t = threadIdx.x, wave = t >> 6, lane = t & 63;
    const int li = lane & 15, lg = lane >> 4;
    const int eg = wave >> 1, ch = wave & 1;
    const int e0b = blockIdx.x * 128;
    uint16_t* wb0 = (uint16_t*)lds;
    uint16_t* wb1 = (uint16_t*)(lds + 16384);
    const uint8_t* wsb = (const uint8_t*)ws;

    int cur = 0;
    auto stage16 = [&](int elemoff){
        uint8_t* dst = (uint8_t*)(cur ? wb0 : wb1) + t * 16;
        const uint8_t* g = wsb + (size_t)elemoff * 2 + t * 16;
        g2l16(g, dst); g2l16(g + 8192, dst + 8192);
    };
    auto stepend = [&](){ __syncthreads(); cur ^= 1; };
    auto curb = [&]() -> const uint16_t* { return cur ? wb1 : wb0; };

    f32x4 acc[2][8];
    #pragma unroll
    for (int ct = 0; ct < 8; ++ct){
        float bv = b_d1[ch * 128 + ct * 16 + li];
        f32x4 iv = {bv, bv, bv, bv};
        acc[0][ct] = iv; acc[1][ct] = iv;
    }

    // prologue: D1 chunk0 (16KB) -> wb0
    {
        const uint8_t* g = wsb + (size_t)OFF_D1 * 2 + t * 16;
        g2l16(g, (uint8_t*)wb0 + t * 16);
        g2l16(g + 8192, (uint8_t*)wb0 + t * 16 + 8192);
    }
    __syncthreads();

    #pragma unroll
    for (int kt = 0; kt < 4; ++kt){
        if (kt < 3) stage16(OFF_D1 + (kt + 1) * 8192);
        bf16x8 a0, a1;
        {
            int ea = e0b + eg * 32 + li;      if (ea >= E) ea = E - 1;
            int eb = e0b + eg * 32 + 16 + li; if (eb >= E) eb = E - 1;
            const float* pa = dual_emb + (size_t)ea * 128 + kt * 32 + lg * 8;
            const float* pb = dual_emb + (size_t)eb * 128 + kt * 32 + lg * 8;
            a0 = pack8(*(const float4v*)pa, *(const float4v*)(pa + 4));
            a1 = pack8(*(const float4v*)pb, *(const float4v*)(pb + 4));
        }
        #pragma unroll
        for (int ct = 0; ct < 8; ++ct){
            bf16x8 b = *(const bf16x8*)(curb() + (ch * 8 + ct) * 512 + lane * 8);
            acc[0][ct] = __builtin_amdgcn_mfma_f32_16x16x32_bf16(a0, b, acc[0][ct], 0, 0, 0);
            acc[1][ct] = __builtin_amdgcn_mfma_f32_16x16x32_bf16(a1, b, acc[1][ct], 0, 0, 0);
        }
        if (kt < 3) stepend();
    }
    // silu -> hbuf (linear bf16 [row][256])
    #pragma unroll
    for (int rt = 0; rt < 2; ++rt)
        #pragma unroll
        for (int r = 0; r < 4; ++r){
            size_t row = (size_t)(e0b + eg * 32 + rt * 16 + lg * 4 + r);
            #pragma unroll
            for (int ct = 0; ct < 8; ++ct)
                hbuf[row * 256 + ch * 128 + ct * 16 + li] = bfc(fsilu(acc[rt][ct][r]));
        }
}

// ---- k_d2: 256 -> 256 + W_do dot -> dpbuf ----
__global__ void __launch_bounds__(512)
k_d2(const float* __restrict__ b_d2, const float* __restrict__ W_do, const float* __restrict__ b_do,
     const uint16_t* __restrict__ ws, const uint16_t* __restrict__ hbuf,
     float* __restrict__ dpbuf, int E)
{
    __shared__ char lds[33792];   // wb 32KB + dpp 1KB
    const int t = threadIdx.x, wave = t >> 6, lane = t & 63;
    const int li = lane & 15, lg = lane >> 4;
    const int eg = wave >> 1, ch = wave & 1;
    const int e0b = blockIdx.x * 128;
    uint16_t* wb0 = (uint16_t*)lds;
    uint16_t* wb1 = (uint16_t*)(lds + 16384);
    float* dpp = (float*)(lds + 32768);    // [2][128]
    const uint8_t* wsb = (const uint8_t*)ws;

    int cur = 0;
    auto stage16 = [&](int elemoff){
        uint8_t* dst = (uint8_t*)(cur ? wb0 : wb1) + t * 16;
        const uint8_t* g = wsb + (size_t)elemoff * 2 + t * 16;
        g2l16(g, dst); g2l16(g + 8192, dst + 8192);
    };
    auto stepend = [&](){ __syncthreads(); cur ^= 1; };
    auto curb = [&]() -> const uint16_t* { return cur ? wb1 : wb0; };

    f32x4 acc[2][8];
    #pragma unroll
    for (int ct = 0; ct < 8; ++ct){
        float bv = b_d2[ch * 128 + ct * 16 + li];
        f32x4 iv = {bv, bv, bv, bv};
        acc[0][ct] = iv; acc[1][ct] = iv;
    }
    {
        const uint8_t* g = wsb + (size_t)OFF_D2 * 2 + t * 16;
        g2l16(g, (uint8_t*)wb0 + t * 16);
        g2l16(g + 8192, (uint8_t*)wb0 + t * 16 + 8192);
    }
    __syncthreads();

    #pragma unroll
    for (int kt = 0; kt < 8; ++kt){
        if (kt < 7) stage16(OFF_D2 + (kt + 1) * 8192);
        bf16x8 a0 = *(const bf16x8*)(hbuf + (size_t)(e0b + eg * 32 + li) * 256 + kt * 32 + lg * 8);
        bf16x8 a1 = *(const bf16x8*)(hbuf + (size_t)(e0b + eg * 32 + 16 + li) * 256 + kt * 32 + lg * 8);
        #pragma unroll
        for (int ct = 0; ct < 8; ++ct){
            bf16x8 b = *(const bf16x8*)(curb() + (ch * 8 + ct) * 512 + lane * 8);
            acc[0][ct] = __builtin_amdgcn_mfma_f32_16x16x32_bf16(a0, b, acc[0][ct], 0, 0, 0);
            acc[1][ct] = __builtin_amdgcn_mfma_f32_16x16x32_bf16(a1, b, acc[1][ct], 0, 0, 0);
        }
        if (kt < 7) stepend();
    }
    #pragma unroll
    for (int rt = 0; rt < 2; ++rt)
        #pragma unroll
        for (int r = 0; r < 4; ++r){
            float s = 0.f;
            #pragma unroll
            for (int ct = 0; ct < 8; ++ct)
                s += fsilu(acc[rt][ct][r]) * W_do[ch * 128 + ct * 16 + li];
            s += __shfl_xor(s, 1); s += __shfl_xor(s, 2);
            s += __shfl_xor(s, 4); s += __shfl_xor(s, 8);
            if (li == 0) dpp[ch * 128 + eg * 32 + rt * 16 + lg * 4 + r] = s;
        }
    __syncthreads();
    if (t < 128) dpbuf[e0b + t] = fsigmoid(dpp[t] + dpp[128 + t] + b_do[0]);
}

// ---- k_f1: feats(387) -> 256, out x1 -> hbuf (overwrite) ----
__global__ void __launch_bounds__(512)
k_f1(const int* __restrict__ edge_index, const float* __restrict__ logits,
     const float* __restrict__ W_f1, const float* __restrict__ b_f1,
     const uint16_t* __restrict__ ws, const uint16_t* __restrict__ nbf,
     const uint16_t* __restrict__ e3buf, const float* __restrict__ dpbuf,
     uint16_t* __restrict__ hbuf, int E)
{
    __shared__ char lds[34816];   // wb 32KB + ps/pd/sidx/didx 2KB
    const int t = threadIdx.x, wave = t >> 6, lane = t & 63;
    const int li = lane & 15, lg = lane >> 4;
    const int eg = wave >> 1, ch = wave & 1;
    const int e0b = blockIdx.x * 128;
    uint16_t* wb0 = (uint16_t*)lds;
    uint16_t* wb1 = (uint16_t*)(lds + 16384);
    float* ps = (float*)(lds + 32768);
    float* pd = (float*)(lds + 33280);
    int* sidx = (int*)(lds + 33792);
    int* didx = (int*)(lds + 34304);
    const uint8_t* wsb = (const uint8_t*)ws;

    if (t < 128) {
        int e = e0b + t; if (e >= E) e = E - 1;
        int s_ = edge_index[e];
        int d_ = edge_index[E + e];
        sidx[t] = s_; didx[t] = d_;
        ps[t] = fsigmoid(logits[s_]);
        pd[t] = fsigmoid(logits[d_]);
    }
    int cur = 0;
    auto stage16 = [&](int elemoff){
        uint8_t* dst = (uint8_t*)(cur ? wb0 : wb1) + t * 16;
        const uint8_t* g = wsb + (size_t)elemoff * 2 + t * 16;
        g2l16(g, dst); g2l16(g + 8192, dst + 8192);
    };
    auto stepend = [&](){ __syncthreads(); cur ^= 1; };
    auto curb = [&]() -> const uint16_t* { return cur ? wb1 : wb0; };

    {
        const uint8_t* g = wsb + (size_t)OFF_F1 * 2 + t * 16;
        g2l16(g, (uint8_t*)wb0 + t * 16);
        g2l16(g + 8192, (uint8_t*)wb0 + t * 16 + 8192);
    }
    __syncthreads();    // also makes ps/pd/sidx/didx visible

    f32x4 acc[2][8];
    {
        #pragma unroll
        for (int ct = 0; ct < 8; ++ct){
            int col = ch * 128 + ct * 16 + li;
            float bv = b_f1[col];
            float t0 = W_f1[384 * 256 + col];
            float t1 = W_f1[385 * 256 + col];
            float t2 = W_f1[386 * 256 + col];
            #pragma unroll
            for (int rt = 0; rt < 2; ++rt)
                #pragma unroll
                for (int r = 0; r < 4; ++r){
                    int row = eg * 32 + rt * 16 + lg * 4 + r;
                    float dv = dpbuf[e0b + row];
                    acc[rt][ct][r] = bv + dv*t0 + ps[row]*t1 + pd[row]*t2;
                }
        }
    }
    int s0 = sidx[eg * 32 + li],  s1 = sidx[eg * 32 + 16 + li];
    int d0 = didx[eg * 32 + li],  d1 = didx[eg * 32 + 16 + li];
    #pragma unroll
    for (int kt = 0; kt < 12; ++kt){
        if (kt < 11) stage16(OFF_F1 + (kt + 1) * 8192);
        bf16x8 a0, a1;
        if (kt < 8){
            int ra = (kt < 4) ? s0 : d0;
            int rb = (kt < 4) ? s1 : d1;
            int ko = (kt & 3) * 32 + lg * 8;
            a0 = *(const bf16x8*)(nbf + (size_t)ra * 128 + ko);
            a1 = *(const bf16x8*)(nbf + (size_t)rb * 128 + ko);
        } else {
            int ko = (kt - 8) * 32 + lg * 8;
            a0 = *(const bf16x8*)(e3buf + (size_t)(e0b + eg * 32 + li) * 128 + ko);
            a1 = *(const bf16x8*)(e3buf + (size_t)(e0b + eg * 32 + 16 + li) * 128 + ko);
        }
        #pragma unroll
        for (int ct = 0; ct < 8; ++ct){
            bf16x8 b = *(const bf16x8*)(curb() + (ch * 8 + ct) * 512 + lane * 8);
            acc[0][ct] = __builtin_amdgcn_mfma_f32_16x16x32_bf16(a0, b, acc[0][ct], 0, 0, 0);
            acc[1][ct] = __builtin_amdgcn_mfma_f32_16x16x32_bf16(a1, b, acc[1][ct], 0, 0, 0);
        }
        if (kt < 11) stepend();
    }
    #pragma unroll
    for (int rt = 0; rt < 2; ++rt)
        #pragma unroll
        for (int r = 0; r < 4; ++r){
            size_t row = (size_t)(e0b + eg * 32 + rt * 16 + lg * 4 + r);
            #pragma unroll
            for (int ct = 0; ct < 8; ++ct)
                hbuf[row * 256 + ch * 128 + ct * 16 + li] = bfc(fsilu(acc[rt][ct][r]));
        }
}

// ---- k_f2: 256 -> 256 + W_bo dot -> out ----
__global__ void __launch_bounds__(512)
k_f2(const float* __restrict__ b_f2, const float* __restrict__ W_bo, const float* __restrict__ b_bo,
     const uint16_t* __restrict__ ws, const uint16_t* __restrict__ hbuf,
     float* __restrict__ out, int E)
{
    __shared__ char lds[33792];
    const int t = threadIdx.x, wave = t >> 6, lane = t & 63;
    const int li = lane & 15, lg = lane >> 4;
    const int eg = wave >> 1, ch = wave & 1;
    const int e0b = blockIdx.x * 128;
    uint16_t* wb0 = (uint16_t*)lds;
    uint16_t* wb1 = (uint16_t*)(lds + 16384);
    float* bop = (float*)(lds + 32768);
    const uint8_t* wsb = (const uint8_t*)ws;

    int cur = 0;
    auto stage16 = [&](int elemoff){
        uint8_t* dst = (uint8_t*)(cur ? wb0 : wb1) + t * 16;
        const uint8_t* g = wsb + (size_t)elemoff * 2 + t * 16;
        g2l16(g, dst); g2l16(g + 8192, dst + 8192);
    };
    auto stepend = [&](){ __syncthreads(); cur ^= 1; };
    auto curb = [&]() -> const uint16_t* { return cur ? wb1 : wb0; };

    f32x4 acc[2][8];
    #pragma unroll
    for (int ct = 0; ct < 8; ++ct){
        float bv = b_f2[ch * 128 + ct * 16 + li];
        f32x4 iv = {bv, bv, bv, bv};
        acc[0][ct] = iv; acc[1][ct] = iv;
    }
    {
        const uint8_t* g = wsb + (size_t)OFF_F2 * 2 + t * 16;
        g2l16(g, (uint8_t*)wb0 + t * 16);
        g2l16(g + 8192, (uint8_t*)wb0 + t * 16 + 8192);
    }
    __syncthreads();

    #pragma unroll
    for (int kt = 0; kt < 8; ++kt){
        if (kt < 7) stage16(OFF_F2 + (kt + 1) * 8192);
        bf16x8 a0 = *(const bf16x8*)(hbuf + (size_t)(e0b + eg * 32 + li) * 256 + kt * 32 + lg * 8);
        bf16x8 a1 = *(const bf16x8*)(hbuf + (size_t)(e0b + eg * 32 + 16 + li) * 256 + kt * 32 + lg * 8);
        #pragma unroll
        for (int ct = 0; ct < 8; ++ct){
            bf16x8 b = *(const bf16x8*)(curb() + (ch * 8 + ct) * 512 + lane * 8);
            acc[0][ct] = __builtin_amdgcn_mfma_f32_16x16x32_bf16(a0, b, acc[0][ct], 0, 0, 0);
            acc[1][ct] = __builtin_amdgcn_mfma_f32_16x16x32_bf16(a1, b, acc[1][ct], 0, 0, 0);
        }
        if (kt < 7) stepend();
    }
    #pragma unroll
    for (int rt = 0; rt < 2; ++rt)
        #pragma unroll
        for (int r = 0; r < 4; ++r){
            float s = 0.f;
            #pragma unroll
            for (int ct = 0; ct < 8; ++ct)
                s += fsilu(acc[rt][ct][r]) * W_bo[ch * 128 + ct * 16 + li];
            s += __shfl_xor(s, 1); s += __shfl_xor(s, 2);
            s += __shfl_xor(s, 4); s += __shfl_xor(s, 8);
            if (li == 0) bop[ch * 128 + eg * 32 + rt * 16 + lg * 4 + r] = s;
        }
    __syncthreads();
    if (t < 128){
        int e = e0b + t;
        if (e < E) out[e] = bop[t] + bop[128 + t] + b_bo[0];
    }
}

// ==================== TIER 2: R10 megakernel (verified 709us) ====================
#define LDS_TOTAL 135168
__global__ void __launch_bounds__(512) __attribute__((amdgpu_waves_per_eu(2, 2)))
bond_fast_kernel(const int* __restrict__ edge_index,
                 const float* __restrict__ edge_attr, const float* __restrict__ dual_emb,
                 const float* __restrict__ logits,
                 const float* __restrict__ b_be1, const float* __restrict__ g_be1, const float* __restrict__ bb_be1,
                 const float* __restrict__ b_be2, const float* __restrict__ g_be2, const float* __restrict__ bb_be2,
                 const float* __restrict__ b_be3, const float* __restrict__ g_be3, const float* __restrict__ bb_be3,
                 const float* __restrict__ b_d1, const float* __restrict__ b_d2,
                 const float* __restrict__ W_do, const float* __restrict__ b_do,
                 const float* __restrict__ W_f1, const float* __restrict__ b_f1,
                 const float* __restrict__ b_f2,
                 const float* __restrict__ W_bo, const float* __restrict__ b_bo,
                 const uint16_t* __restrict__ ws, float* __restrict__ out, int E)
{
    __shared__ char lds[LDS_TOTAL];
    const int t    = threadIdx.x;
    const int wave = t >> 6;
    const int lane = t & 63;
    const int li   = lane & 15, lg = lane >> 4;
    const int eg   = wave >> 1;
    const int ch   = wave & 1;
    const int e0b  = blockIdx.x * 128;

    char* bufE = lds;
    char* h256 = lds + 32768;
    uint16_t* wb0 = (uint16_t*)(lds + 98304);
    uint16_t* wb1 = (uint16_t*)(lds + 114688);
    float* ps  = (float*)(lds + 131072);
    float* pd  = (float*)(lds + 131584);
    int* sidx  = (int*)(lds + 132096);
    int* didx  = (int*)(lds + 132608);
    float* dpp = (float*)(lds + 133120);
    float* bop = (float*)(lds + 134144);

    const uint8_t*  wsb = (const uint8_t*)ws;
    const uint16_t* nbf = ws + WS_ELEMS;

    if (t < 128) {
        int e = e0b + t; if (e >= E) e = E - 1;
        int s_ = edge_index[e];
        int d_ = edge_index[E + e];
        sidx[t] = s_; didx[t] = d_;
        ps[t] = fsigmoid(logits[s_]);
        pd[t] = fsigmoid(logits[d_]);
    }

    int cur = 0;
    auto stageW = [&](int elemoff, int big){
        uint8_t* dst = (uint8_t*)(cur ? wb0 : wb1) + t * 16;
        const uint8_t* g = wsb + (size_t)elemoff * 2 + t * 16;
        g2l16(g, dst);
        if (big) g2l16(g + 8192, dst + 8192);
    };
    auto stepend = [&](){ __syncthreads(); cur ^= 1; };
    auto curbuf  = [&]() -> const uint16_t* { return cur ? wb1 : wb0; };

    f32x4 acc[2][8];

    auto ldf = [&](const uint16_t* w, int fid) -> bf16x8 {
        return *(const bf16x8*)(w + fid * 512 + lane * 8);
    };
    auto grpBE = [&](const uint16_t* w, bf16x8 a0){
        #pragma unroll
        for (int ct = 0; ct < 8; ++ct){
            bf16x8 b = ldf(w, ct);
            acc[0][ct] = __builtin_amdgcn_mfma_f32_16x16x32_bf16(a0, b, acc[0][ct], 0, 0, 0);
        }
    };
    auto grp256 = [&](const uint16_t* w, bf16x8 a0, bf16x8 a1){
        #pragma unroll
        for (int ct = 0; ct < 8; ++ct){
            bf16x8 b = ldf(w, ch * 8 + ct);
            acc[0][ct] = __builtin_amdgcn_mfma_f32_16x16x32_bf16(a0, b, acc[0][ct], 0, 0, 0);
            acc[1][ct] = __builtin_amdgcn_mfma_f32_16x16x32_bf16(a1, b, acc[1][ct], 0, 0, 0);
        }
    };
    auto initBE = [&](const float* b){
        #pragma unroll
        for (int ct = 0; ct < 8; ++ct){
            float bv = b[li + 16 * ct];
            f32x4 iv = {bv, bv, bv, bv};
            acc[0][ct] = iv;
        }
    };
    auto init256 = [&](const float* b){
        #pragma unroll
        for (int ct = 0; ct < 8; ++ct){
            float bv = b[ch * 128 + ct * 16 + li];
            f32x4 iv = {bv, bv, bv, bv};
            acc[0][ct] = iv; acc[1][ct] = iv;
        }
    };
    auto eb_read = [&](int row, int kt) -> bf16x8 {
        int off = row * 256 + (kt * 32 + lg * 8) * 2;
        return *(const bf16x8*)(bufE + (off ^ ((row & 7) << 4)));
    };
    auto h2_read = [&](int row, int kt) -> bf16x8 {
        int off = row * 512 + (kt * 32 + lg * 8) * 2;
        return *(const bf16x8*)(h256 + (off ^ ((row & 7) << 4)));
    };
    auto lnstoreBE = [&](const float* g, const float* bb){
        #pragma unroll
        for (int r = 0; r < 4; ++r){
            float s = 0.f, q = 0.f;
            #pragma unroll
            for (int ct = 0; ct < 8; ++ct){ float v = acc[0][ct][r]; s += v; q += v*v; }
            s += __shfl_xor(s, 1); q += __shfl_xor(q, 1);
            s += __shfl_xor(s, 2); q += __shfl_xor(q, 2);
            s += __shfl_xor(s, 4); q += __shfl_xor(q, 4);
            s += __shfl_xor(s, 8); q += __shfl_xor(q, 8);
            float mu = s * 0.0078125f;
            float var = q * 0.0078125f - mu * mu;
            float rs = rsqrtf(var + 1e-5f);
            int row = wave * 16 + lg * 4 + r;
            int rswz = (row & 7) << 4;
            #pragma unroll
            for (int ct = 0; ct < 8; ++ct){
                int col = li + 16 * ct;
                float v = (acc[0][ct][r] - mu) * rs * g[col] + bb[col];
                int off = row * 256 + col * 2;
                *(uint16_t*)(bufE + (off ^ rswz)) = bfc(fsilu(v));
            }
        }
    };
    auto silustore256 = [&](){
        #pragma unroll
        for (int rt = 0; rt < 2; ++rt){
            #pragma unroll
            for (int r = 0; r < 4; ++r){
                int row = eg * 32 + rt * 16 + lg * 4 + r;
                int rswz = (row & 7) << 4;
                #pragma unroll
                for (int ct = 0; ct < 8; ++ct){
                    int off = row * 512 + (ch * 128 + ct * 16 + li) * 2;
                    *(uint16_t*)(h256 + (off ^ rswz)) = bfc(fsilu(acc[rt][ct][r]));
                }
            }
        }
    };

    {
        const uint8_t* g = wsb + t * 16;
        g2l16(g, (uint8_t*)wb0 + t * 16);
    }
    __syncthreads();

    {
        stageW(OFF_BE2, 0);
        bf16x8 aE = {0,0,0,0,0,0,0,0};
        if (lg < 2){
            int ea = e0b + wave * 16 + li; if (ea >= E) ea = E - 1;
            const float* pa = edge_attr + (size_t)ea * 16 + lg * 8;
            aE = pack8(*(const float4v*)pa, *(const float4v*)(pa + 4));
        }
        initBE(b_be1);
        grpBE(curbuf(), aE);
        lnstoreBE(g_be1, bb_be1);
        stepend();
    }

    initBE(b_be2);
    #pragma unroll
    for (int kt = 0; kt < 4; ++kt){
        if (kt < 3) stageW(OFF_BE2 + (kt + 1) * 4096, 0);
        else        stageW(OFF_BE3, 0);
        grpBE(curbuf(), eb_read(wave * 16 + li, kt));
        if (kt == 3) lnstoreBE(g_be2, bb_be2);
        stepend();
    }
    initBE(b_be3);
    #pragma unroll
    for (int kt = 0; kt < 4; ++kt){
        if (kt < 3) stageW(OFF_BE3 + (kt + 1) * 4096, 0);
        else        stageW(OFF_D1, 1);
        grpBE(curbuf(), eb_read(wave * 16 + li, kt));
        if (kt == 3) lnstoreBE(g_be3, bb_be3);
        stepend();
    }

    init256(b_d1);
    #pragma unroll
    for (int kt = 0; kt < 4; ++kt){
        float4v va0, va1, vb0, vb1;
        {
            int ea = e0b + eg * 32 + li;      if (ea >= E) ea = E - 1;
            int eb = e0b + eg * 32 + 16 + li; if (eb >= E) eb = E - 1;
            const float* pa = dual_emb + (size_t)ea * 128 + kt * 32 + lg * 8;
            const float* pb = dual_emb + (size_t)eb * 128 + kt * 32 + lg * 8;
            va0 = *(const float4v*)pa; va1 = *(const float4v*)(pa + 4);
            vb0 = *(const float4v*)pb; vb1 = *(const float4v*)(pb + 4);
        }
        if (kt < 3) stageW(OFF_D1 + (kt + 1) * 8192, 1);
        else        stageW(OFF_D2, 1);
        grp256(curbuf(), pack8(va0, va1), pack8(vb0, vb1));
        if (kt == 3) silustore256();
        stepend();
    }

    init256(b_d2);
    #pragma unroll
    for (int kt = 0; kt < 8; ++kt){
        if (kt < 7) stageW(OFF_D2 + (kt + 1) * 8192, 1);
        else        stageW(OFF_F1, 1);
        grp256(curbuf(), h2_read(eg * 32 + li, kt), h2_read(eg * 32 + 16 + li, kt));
        if (kt == 7){
            #pragma unroll
            for (int rt = 0; rt < 2; ++rt){
                #pragma unroll
                for (int r = 0; r < 4; ++r){
                    float s = 0.f;
                    #pragma unroll
                    for (int ct = 0; ct < 8; ++ct)
                        s += fsilu(acc[rt][ct][r]) * W_do[ch * 128 + ct * 16 + li];
                    s += __shfl_xor(s, 1); s += __shfl_xor(s, 2);
                    s += __shfl_xor(s, 4); s += __shfl_xor(s, 8);
                    if (li == 0) dpp[ch * 128 + eg * 32 + rt * 16 + lg * 4 + r] = s;
                }
            }
        }
        stepend();
    }

    {
        {
            float bdo0 = b_do[0];
            #pragma unroll
            for (int ct = 0; ct < 8; ++ct){
                int col = ch * 128 + ct * 16 + li;
                float bv = b_f1[col];
                float t0 = W_f1[384 * 256 + col];
                float t1 = W_f1[385 * 256 + col];
                float t2 = W_f1[386 * 256 + col];
                #pragma unroll
                for (int rt = 0; rt < 2; ++rt)
                    #pragma unroll
                    for (int r = 0; r < 4; ++r){
                        int row = eg * 32 + rt * 16 + lg * 4 + r;
                        float dv = fsigmoid(dpp[row] + dpp[128 + row] + bdo0);
                        acc[rt][ct][r] = bv + dv*t0 + ps[row]*t1 + pd[row]*t2;
                    }
            }
        }
        int s0 = sidx[eg * 32 + li],      s1 = sidx[eg * 32 + 16 + li];
        int d0 = didx[eg * 32 + li],      d1 = didx[eg * 32 + 16 + li];
        #pragma unroll
        for (int kt = 0; kt < 12; ++kt){
            bf16x8 a0, a1;
            if (kt < 8){
                int ra = (kt < 4) ? s0 : d0;
                int rb = (kt < 4) ? s1 : d1;
                int ko = (kt & 3) * 32 + lg * 8;
                a0 = *(const bf16x8*)(nbf + (size_t)ra * 128 + ko);
                a1 = *(const bf16x8*)(nbf + (size_t)rb * 128 + ko);
            } else {
                a0 = eb_read(eg * 32 + li, kt - 8);
                a1 = eb_read(eg * 32 + 16 + li, kt - 8);
            }
            if (kt < 11) stageW(OFF_F1 + (kt + 1) * 8192, 1);
            else         stageW(OFF_F2, 1);
            grp256(curbuf(), a0, a1);
            if (kt == 11) silustore256();
            stepend();
        }
    }

    init256(b_f2);
    #pragma unroll
    for (int kt = 0; kt < 8; ++kt){
        if (kt < 7) stageW(OFF_F2 + (kt + 1) * 8192, 1);
        grp256(curbuf(), h2_read(eg * 32 + li, kt), h2_read(eg * 32 + 16 + li, kt));
        if (kt == 7){
            #pragma unroll
            for (int rt = 0; rt < 2; ++rt){
                #pragma unroll
                for (int r = 0; r < 4; ++r){
                    float s = 0.f;
                    #pragma unroll
                    for (int ct = 0; ct < 8; ++ct)
                        s += fsilu(acc[rt][ct][r]) * W_bo[ch * 128 + ct * 16 + li];
                    s += __shfl_xor(s, 1); s += __shfl_xor(s, 2);
                    s += __shfl_xor(s, 4); s += __shfl_xor(s, 8);
                    if (li == 0) bop[ch * 128 + eg * 32 + rt * 16 + lg * 4 + r] = s;
                }
            }
        } else {
            stepend();
        }
    }
    __syncthreads();
    if (t < 128){
        int e = e0b + t;
        if (e < E) out[e] = bop[t] + bop[128 + t] + b_bo[0];
    }
}

// ==================== TIER 3: R6 self-contained fallback (no ws) ====================
__global__ void __launch_bounds__(512) __attribute__((amdgpu_waves_per_eu(2, 2)))
bond_fused_kernel(const float* __restrict__ node_emb, const int* __restrict__ edge_index,
                  const float* __restrict__ edge_attr, const float* __restrict__ dual_emb,
                  const float* __restrict__ logits,
                  const float* __restrict__ W_be1, const float* __restrict__ b_be1,
                  const float* __restrict__ g_be1, const float* __restrict__ bb_be1,
                  const float* __restrict__ W_be2, const float* __restrict__ b_be2,
                  const float* __restrict__ g_be2, const float* __restrict__ bb_be2,
                  const float* __restrict__ W_be3, const float* __restrict__ b_be3,
                  const float* __restrict__ g_be3, const float* __restrict__ bb_be3,
                  const float* __restrict__ W_d1, const float* __restrict__ b_d1,
                  const float* __restrict__ W_d2, const float* __restrict__ b_d2,
                  const float* __restrict__ W_do, const float* __restrict__ b_do,
                  const float* __restrict__ W_f1, const float* __restrict__ b_f1,
                  const float* __restrict__ W_f2, const float* __restrict__ b_f2,
                  const float* __restrict__ W_bo, const float* __restrict__ b_bo,
                  float* __restrict__ out, int E)
{
    __shared__ char lds[LDS_TOTAL];
    const int t    = threadIdx.x;
    const int wave = t >> 6;
    const int lane = t & 63;
    const int li   = lane & 15, lg = lane >> 4;
    const int eg   = wave >> 1;
    const int ch   = wave & 1;
    const int e0b  = blockIdx.x * 128;

    char* bufE = lds;
    char* h256 = lds + 32768;
    uint16_t* wb0 = (uint16_t*)(lds + 98304);
    uint16_t* wb1 = (uint16_t*)(lds + 114688);
    float* ps  = (float*)(lds + 131072);
    float* pd  = (float*)(lds + 131584);
    int* sidx  = (int*)(lds + 132096);
    int* didx  = (int*)(lds + 132608);
    float* dpp = (float*)(lds + 133120);
    float* bop = (float*)(lds + 134144);

    if (t < 128) {
        int e = e0b + t; if (e >= E) e = E - 1;
        int s_ = edge_index[e];
        int d_ = edge_index[E + e];
        sidx[t] = s_; didx[t] = d_;
        ps[t] = fsigmoid(logits[s_]);
        pd[t] = fsigmoid(logits[d_]);
    }

    float sr[2][8];
    auto issueW256 = [&](const float* W, int kbase){
        #pragma unroll
        for (int h = 0; h < 2; ++h){
            const float* p = W + (size_t)(kbase + lg * 8) * 256 + (wave + 8*h) * 16 + li;
            #pragma unroll
            for (int j = 0; j < 8; ++j) sr[h][j] = p[j * 256];
        }
    };
    auto issueW128 = [&](const float* W, int kbase, int K){
        const float* p = W + (size_t)(kbase + lg * 8) * 128 + wave * 16 + li;
        #pragma unroll
        for (int j = 0; j < 8; ++j)
            sr[0][j] = (kbase + lg * 8 + j < K) ? p[j * 128] : 0.f;
    };
    auto commitW = [&](uint16_t* dst, int nh){
        #pragma unroll
        for (int h = 0; h < 2; ++h){
            if (h < nh){
                uint4 w;
                w.x = pk2(sr[h][0], sr[h][1]); w.y = pk2(sr[h][2], sr[h][3]);
                w.z = pk2(sr[h][4], sr[h][5]); w.w = pk2(sr[h][6], sr[h][7]);
                *(uint4*)(dst + (wave + 8*h) * 512 + lane * 8) = w;
            }
        }
    };

    int cur = 0;
    auto stepend = [&](int mode){
        if (mode) commitW(cur ? wb0 : wb1, mode == 128 ? 1 : 2);
        __syncthreads();
        cur ^= 1;
    };
    auto curbuf = [&]() -> const uint16_t* { return cur ? wb1 : wb0; };

    f32x4 acc[2][8];

    auto ldf = [&](const uint16_t* w, int fid) -> bf16x8 {
        return *(const bf16x8*)(w + fid * 512 + lane * 8);
    };
    auto grpBE = [&](const uint16_t* w, bf16x8 a0){
        #pragma unroll
        for (int ct = 0; ct < 8; ++ct){
            bf16x8 b = ldf(w, ct);
            acc[0][ct] = __builtin_amdgcn_mfma_f32_16x16x32_bf16(a0, b, acc[0][ct], 0, 0, 0);
        }
    };
    auto grp256 = [&](const uint16_t* w, bf16x8 a0, bf16x8 a1){
        #pragma unroll
        for (int ct = 0; ct < 8; ++ct){
            bf16x8 b = ldf(w, ch * 8 + ct);
            acc[0][ct] = __builtin_amdgcn_mfma_f32_16x16x32_bf16(a0, b, acc[0][ct], 0, 0, 0);
            acc[1][ct] = __builtin_amdgcn_mfma_f32_16x16x32_bf16(a1, b, acc[1][ct], 0, 0, 0);
        }
    };
    auto initBE = [&](const float* b){
        #pragma unroll
        for (int ct = 0; ct < 8; ++ct){
            float bv = b[li + 16 * ct];
            f32x4 iv = {bv, bv, bv, bv};
            acc[0][ct] = iv;
        }
    };
    auto init256 = [&](const float* b){
        #pragma unroll
        for (int ct = 0; ct < 8; ++ct){
            float bv = b[ch * 128 + ct * 16 + li];
            f32x4 iv = {bv, bv, bv, bv};
            acc[0][ct] = iv; acc[1][ct] = iv;
        }
    };
    auto eb_read = [&](int row, int kt) -> bf16x8 {
        int off = row * 256 + (kt * 32 + lg * 8) * 2;
        return *(const bf16x8*)(bufE + (off ^ ((row & 7) << 4)));
    };
    auto h2_read = [&](int row, int kt) -> bf16x8 {
        int off = row * 512 + (kt * 32 + lg * 8) * 2;
        return *(const bf16x8*)(h256 + (off ^ ((row & 7) << 4)));
    };
    auto lnstoreBE = [&](const float* g, const float* bb){
        #pragma unroll
        for (int r = 0; r < 4; ++r){
            float s = 0.f, q = 0.f;
            #pragma unroll
            for (int ct = 0; ct < 8; ++ct){ float v = acc[0][ct][r]; s += v; q += v*v; }
            s += __shfl_xor(s, 1); q += __shfl_xor(q, 1);
            s += __shfl_xor(s, 2); q += __shfl_xor(q, 2);
            s += __shfl_xor(s, 4); q += __shfl_xor(q, 4);
            s += __shfl_xor(s, 8); q += __shfl_xor(q, 8);
            float mu = s * 0.0078125f;
            float var = q * 0.0078125f - mu * mu;
            float rs = rsqrtf(var + 1e-5f);
            int row = wave * 16 + lg * 4 + r;
            int rswz = (row & 7) << 4;
            #pragma unroll
            for (int ct = 0; ct < 8; ++ct){
                int col = li + 16 * ct;
                float v = (acc[0][ct][r] - mu) * rs * g[col] + bb[col];
                int off = row * 256 + col * 2;
                *(uint16_t*)(bufE + (off ^ rswz)) = bfc(fsilu(v));
            }
        }
    };
    auto silustore256 = [&](){
        #pragma unroll
        for (int rt = 0; rt < 2; ++rt){
            #pragma unroll
            for (int r = 0; r < 4; ++r){
                int row = eg * 32 + rt * 16 + lg * 4 + r;
                int rswz = (row & 7) << 4;
                #pragma unroll
                for (int ct = 0; ct < 8; ++ct){
                    int off = row * 512 + (ch * 128 + ct * 16 + li) * 2;
                    *(uint16_t*)(h256 + (off ^ rswz)) = bfc(fsilu(acc[rt][ct][r]));
                }
            }
        }
    };

    issueW128(W_be1, 0, 16);
    commitW(wb0, 1);
    __syncthreads();

    {
        bf16x8 aE = {0,0,0,0,0,0,0,0};
        if (lg < 2){
            int ea = e0b + wave * 16 + li; if (ea >= E) ea = E - 1;
            const float* pa = edge_attr + (size_t)ea * 16 + lg * 8;
            aE = pack8(*(const float4v*)pa, *(const float4v*)(pa + 4));
        }
        issueW128(W_be2, 0, 128);
        initBE(b_be1);
        grpBE(curbuf(), aE);
        lnstoreBE(g_be1, bb_be1);
        stepend(128);
    }

    initBE(b_be2);
    #pragma unroll 1
    for (int kt = 0; kt < 4; ++kt){
        if (kt < 3) issueW128(W_be2, (kt + 1) * 32, 128);
        else        issueW128(W_be3, 0, 128);
        grpBE(curbuf(), eb_read(wave * 16 + li, kt));
        if (kt == 3) lnstoreBE(g_be2, bb_be2);
        stepend(128);
    }
    initBE(b_be3);
    #pragma unroll 1
    for (int kt = 0; kt < 4; ++kt){
        if (kt < 3) issueW128(W_be3, (kt + 1) * 32, 128);
        else        issueW256(W_d1, 0);
        grpBE(curbuf(), eb_read(wave * 16 + li, kt));
        if (kt == 3) lnstoreBE(g_be3, bb_be3);
        stepend(kt < 3 ? 128 : 256);
    }

    init256(b_d1);
    #pragma unroll 1
    for (int kt = 0; kt < 4; ++kt){
        float4v va0, va1, vb0, vb1;
        {
            int ea = e0b + eg * 32 + li;      if (ea >= E) ea = E - 1;
            int eb = e0b + eg * 32 + 16 + li; if (eb >= E) eb = E - 1;
            const float* pa = dual_emb + (size_t)ea * 128 + kt * 32 + lg * 8;
            const float* pb = dual_emb + (size_t)eb * 128 + kt * 32 + lg * 8;
            va0 = *(const float4v*)pa; va1 = *(const float4v*)(pa + 4);
            vb0 = *(const float4v*)pb; vb1 = *(const float4v*)(pb + 4);
        }
        if (kt < 3) issueW256(W_d1, (kt + 1) * 32);
        else        issueW256(W_d2, 0);
        grp256(curbuf(), pack8(va0, va1), pack8(vb0, vb1));
        if (kt == 3) silustore256();
        stepend(256);
    }

    init256(b_d2);
    #pragma unroll 1
    for (int kt = 0; kt < 8; ++kt){
        if (kt < 7) issueW256(W_d2, (kt + 1) * 32);
        else        issueW256(W_f1, 0);
        grp256(curbuf(), h2_read(eg * 32 + li, kt), h2_read(eg * 32 + 16 + li, kt));
        if (kt == 7){
            #pragma unroll
            for (int rt = 0; rt < 2; ++rt){
                #pragma unroll
                for (int r = 0; r < 4; ++r){
                    float s = 0.f;
                    #pragma unroll
                    for (int ct = 0; ct < 8; ++ct)
                        s += fsilu(acc[rt][ct][r]) * W_do[ch * 128 + ct * 16 + li];
                    s += __shfl_xor(s, 1); s += __shfl_xor(s, 2);
                    s += __shfl_xor(s, 4); s += __shfl_xor(s, 8);
                    if (li == 0) dpp[ch * 128 + eg * 32 + rt * 16 + lg * 4 + r] = s;
                }
            }
        }
        stepend(256);
    }

    {
        {
            float bdo0 = b_do[0];
            #pragma unroll
            for (int ct = 0; ct < 8; ++ct){
                int col = ch * 128 + ct * 16 + li;
                float bv = b_f1[col];
                float t0 = W_f1[384 * 256 + col];
                float t1 = W_f1[385 * 256 + col];
                float t2 = W_f1[386 * 256 + col];
                #pragma unroll
                for (int rt = 0; rt < 2; ++rt)
                    #pragma unroll
                    for (int r = 0; r < 4; ++r){
                        int row = eg * 32 + rt * 16 + lg * 4 + r;
                        float dv = fsigmoid(dpp[row] + dpp[128 + row] + bdo0);
                        acc[rt][ct][r] = bv + dv*t0 + ps[row]*t1 + pd[row]*t2;
                    }
            }
        }
        int s0 = sidx[eg * 32 + li],      s1 = sidx[eg * 32 + 16 + li];
        int d0 = didx[eg * 32 + li],      d1 = didx[eg * 32 + 16 + li];
        #pragma unroll 1
        for (int kt = 0; kt < 12; ++kt){
            bf16x8 a0, a1;
            if (kt < 8){
                int ra = (kt < 4) ? s0 : d0;
                int rb = (kt < 4) ? s1 : d1;
                int ko = (kt & 3) * 32 + lg * 8;
                const float* pa = node_emb + (size_t)ra * 128 + ko;
                const float* pb = node_emb + (size_t)rb * 128 + ko;
                a0 = pack8(*(const float4v*)pa, *(const float4v*)(pa + 4));
                a1 = pack8(*(const float4v*)pb, *(const float4v*)(pb + 4));
            } else {
                a0 = eb_read(eg * 32 + li, kt - 8);
                a1 = eb_read(eg * 32 + 16 + li, kt - 8);
            }
            if (kt < 11) issueW256(W_f1, (kt + 1) * 32);
            else         issueW256(W_f2, 0);
            grp256(curbuf(), a0, a1);
            if (kt == 11) silustore256();
            stepend(256);
        }
    }

    init256(b_f2);
    #pragma unroll 1
    for (int kt = 0; kt < 8; ++kt){
        if (kt < 7) issueW256(W_f2, (kt + 1) * 32);
        grp256(curbuf(), h2_read(eg * 32 + li, kt), h2_read(eg * 32 + 16 + li, kt));
        if (kt == 7){
            #pragma unroll
            for (int rt = 0; rt < 2; ++rt){
                #pragma unroll
                for (int r = 0; r < 4; ++r){
                    float s = 0.f;
                    #pragma unroll
                    for (int ct = 0; ct < 8; ++ct)
                        s += fsilu(acc[rt][ct][r]) * W_bo[ch * 128 + ct * 16 + li];
                    s += __shfl_xor(s, 1); s += __shfl_xor(s, 2);
                    s += __shfl_xor(s, 4); s += __shfl_xor(s, 8);
                    if (li == 0) bop[ch * 128 + eg * 32 + rt * 16 + lg * 4 + r] = s;
                }
            }
        } else {
            stepend(256);
        }
    }
    __syncthreads();
    if (t < 128){
        int e = e0b + t;
        if (e < E) out[e] = bop[t] + bop[128 + t] + b_bo[0];
    }
}

extern "C" void kernel_launch(void* const* d_in, const int* in_sizes, int n_in,
                              void* d_out, int out_size, void* d_ws, size_t ws_size,
                              hipStream_t stream) {
    const float* node_emb   = (const float*)d_in[0];
    const int*   edge_index = (const int*)d_in[1];
    const float* edge_attr  = (const float*)d_in[2];
    const float* dual_emb   = (const float*)d_in[3];
    const float* logits     = (const float*)d_in[4];
    const float* W_be1 = (const float*)d_in[5];
    const float* b_be1 = (const float*)d_in[6];
    const float* g_be1 = (const float*)d_in[7];
    const float* bb_be1= (const float*)d_in[8];
    const float* W_be2 = (const float*)d_in[9];
    const float* b_be2 = (const float*)d_in[10];
    const float* g_be2 = (const float*)d_in[11];
    const float* bb_be2= (const float*)d_in[12];
    const float* W_be3 = (const float*)d_in[13];
    const float* b_be3 = (const float*)d_in[14];
    const float* g_be3 = (const float*)d_in[15];
    const float* bb_be3= (const float*)d_in[16];
    const float* W_d1  = (const float*)d_in[17];
    const float* b_d1  = (const float*)d_in[18];
    const float* W_d2  = (const float*)d_in[19];
    const float* b_d2  = (const float*)d_in[20];
    const float* W_do  = (const float*)d_in[21];
    const float* b_do  = (const float*)d_in[22];
    const float* W_f1  = (const float*)d_in[23];
    const float* b_f1  = (const float*)d_in[24];
    const float* W_f2  = (const float*)d_in[25];
    const float* b_f2  = (const float*)d_in[26];
    const float* W_bo  = (const float*)d_in[27];
    const float* b_bo  = (const float*)d_in[28];
    float* out = (float*)d_out;

    int E = in_sizes[2] / 16;
    int nblocks = (E + 127) / 128;
    size_t Epad = (size_t)nblocks * 128;
    size_t nodeElems = (size_t)in_sizes[0];
    size_t wsNeedSmall = ((size_t)WS_ELEMS + nodeElems) * 2;
    size_t wsNeedBig = ((size_t)WS_ELEMS + nodeElems + Epad * 128 + Epad * 256) * 2 + Epad * 4;

    if (ws_size >= wsNeedBig) {
        uint16_t* ws16  = (uint16_t*)d_ws;
        uint16_t* nbf_g = ws16 + WS_ELEMS;
        uint16_t* e3buf = nbf_g + nodeElems;
        uint16_t* hbuf  = e3buf + Epad * 128;
        float*    dpbuf = (float*)(hbuf + Epad * 256);
        prep_w<<<dim3((WS_ELEMS + 255) / 256), dim3(256), 0, stream>>>(
            W_be1, W_be2, W_be3, W_d1, W_d2, W_f1, W_f2, ws16);
        prep_n<<<dim3((int)((nodeElems + 255) / 256)), dim3(256), 0, stream>>>(
            node_emb, nbf_g, (int)nodeElems);
        k_be<<<dim3(nblocks), dim3(512), 0, stream>>>(
            edge_attr, b_be1, g_be1, bb_be1, b_be2, g_be2, bb_be2,
            b_be3, g_be3, bb_be3, ws16, e3buf, E);
        k_d1<<<dim3(nblocks), dim3(512), 0, stream>>>(dual_emb, b_d1, ws16, hbuf, E);
        k_d2<<<dim3(nblocks), dim3(512), 0, stream>>>(b_d2, W_do, b_do, ws16, hbuf, dpbuf, E);
        k_f1<<<dim3(nblocks), dim3(512), 0, stream>>>(
            edge_index, logits, W_f1, b_f1, ws16, nbf_g, e3buf, dpbuf, hbuf, E);
        k_f2<<<dim3(nblocks), dim3(512), 0, stream>>>(b_f2, W_bo, b_bo, ws16, hbuf, out, E);
    } else if (ws_size >= wsNeedSmall) {
        uint16_t* ws16 = (uint16_t*)d_ws;
        prep_w<<<dim3((WS_ELEMS + 255) / 256), dim3(256), 0, stream>>>(
            W_be1, W_be2, W_be3, W_d1, W_d2, W_f1, W_f2, ws16);
        prep_n<<<dim3((int)((nodeElems + 255) / 256)), dim3(256), 0, stream>>>(
            node_emb, ws16 + WS_ELEMS, (int)nodeElems);
        bond_fast_kernel<<<dim3(nblocks), dim3(512), 0, stream>>>(
            edge_index, edge_attr, dual_emb, logits,
            b_be1, g_be1, bb_be1,
            b_be2, g_be2, bb_be2,
            b_be3, g_be3, bb_be3,
            b_d1, b_d2, W_do, b_do,
            W_f1, b_f1, b_f2, W_bo, b_bo,
            ws16, out, E);
    } else {
        bond_fused_kernel<<<dim3(nblocks), dim3(512), 0, stream>>>(
            node_emb, edge_index, edge_attr, dual_emb, logits,
            W_be1, b_be1, g_be1, bb_be1,
            W_be2, b_be2, g_be2, bb_be2,
            W_be3, b_be3, g_be3, bb_be3,
            W_d1, b_d1, W_d2, b_d2, W_do, b_do,
            W_f1, b_f1, W_f2, b_f2, W_bo, b_bo,
            out, E);
    }
}

// Round 20
// 690.869 us; speedup vs baseline: 1.0415x; 1.0415x over previous
//
#include <hip/hip_runtime.h>
#include <hip/hip_bf16.h>
#include <stdint.h>

typedef __attribute__((ext_vector_type(8))) short bf16x8;
typedef __attribute__((ext_vector_type(4))) float f32x4;
typedef __attribute__((ext_vector_type(4))) float float4v;

__device__ __forceinline__ uint16_t bfc(float x){
    __hip_bfloat16 h = __float2bfloat16(x);
    return __builtin_bit_cast(uint16_t, h);
}
__device__ __forceinline__ uint32_t pk2(float a, float b){
    return (uint32_t)bfc(a) | ((uint32_t)bfc(b) << 16);
}
__device__ __forceinline__ float fsigmoid(float x){ return 1.0f / (1.0f + __expf(-x)); }
__device__ __forceinline__ float fsilu(float x){ return x * fsigmoid(x); }

__device__ __forceinline__ bf16x8 pack8(float4v lo, float4v hi){
    bf16x8 r;
    r[0]=(short)bfc(lo[0]); r[1]=(short)bfc(lo[1]);
    r[2]=(short)bfc(lo[2]); r[3]=(short)bfc(lo[3]);
    r[4]=(short)bfc(hi[0]); r[5]=(short)bfc(hi[1]);
    r[6]=(short)bfc(hi[2]); r[7]=(short)bfc(hi[3]);
    return r;
}

// ---------------- weight prep (R2-validated fragpos map) ----------------
#define SZ_BE1 4096
#define SZ_128 16384
#define SZ_D1  32768
#define SZ_D2  65536
#define SZ_F1  98304
#define OFF_BE1 0
#define OFF_BE2 (OFF_BE1 + SZ_BE1)    // 4096
#define OFF_BE3 (OFF_BE2 + SZ_128)    // 20480
#define OFF_D1  (OFF_BE3 + SZ_128)    // 36864
#define OFF_D2  (OFF_D1 + SZ_D1)      // 69632
#define OFF_F1  (OFF_D2 + SZ_D2)      // 135168
#define OFF_F2  (OFF_F1 + SZ_F1)      // 233472
#define WS_ELEMS (OFF_F2 + SZ_D2)     // 299008 bf16 elems = 598016 B

__device__ __forceinline__ int fragpos(int k, int c, int OUT){
    int kt = k >> 5, ct = c >> 4;
    int fid = kt * (OUT >> 4) + ct;
    int ln = ((k & 31) >> 3) * 16 + (c & 15);
    return fid * 512 + ln * 8 + (k & 7);
}

__global__ void __launch_bounds__(256)
prep_w(const float* __restrict__ Wbe1, const float* __restrict__ Wbe2,
       const float* __restrict__ Wbe3, const float* __restrict__ Wd1,
       const float* __restrict__ Wd2,  const float* __restrict__ Wf1,
       const float* __restrict__ Wf2,  uint16_t* __restrict__ ws){
    int t = blockIdx.x * 256 + threadIdx.x;
    if (t >= WS_ELEMS) return;
    if (t < OFF_BE2) {                        // be1: K padded 16 -> 32
        int u = t;            int k = u >> 7, c = u & 127;
        float v = (k < 16) ? Wbe1[k * 128 + c] : 0.0f;
        ws[OFF_BE1 + fragpos(k, c, 128)] = bfc(v);
    } else if (t < OFF_BE3) {
        int u = t - OFF_BE2;  int k = u >> 7, c = u & 127;
        ws[OFF_BE2 + fragpos(k, c, 128)] = bfc(Wbe2[u]);
    } else if (t < OFF_D1) {
        int u = t - OFF_BE3;  int k = u >> 7, c = u & 127;
        ws[OFF_BE3 + fragpos(k, c, 128)] = bfc(Wbe3[u]);
    } else if (t < OFF_D2) {
        int u = t - OFF_D1;   int k = u >> 8, c = u & 255;
        ws[OFF_D1 + fragpos(k, c, 256)] = bfc(Wd1[u]);
    } else if (t < OFF_F1) {
        int u = t - OFF_D2;   int k = u >> 8, c = u & 255;
        ws[OFF_D2 + fragpos(k, c, 256)] = bfc(Wd2[u]);
    } else if (t < OFF_F2) {                  // f1 rows 0..383 only
        int u = t - OFF_F1;   int k = u >> 8, c = u & 255;
        ws[OFF_F1 + fragpos(k, c, 256)] = bfc(Wf1[u]);
    } else {
        int u = t - OFF_F2;   int k = u >> 8, c = u & 255;
        ws[OFF_F2 + fragpos(k, c, 256)] = bfc(Wf2[u]);
    }
}

__global__ void __launch_bounds__(256)
prep_n(const float* __restrict__ src, uint16_t* __restrict__ dst, int n){
    int t = blockIdx.x * 256 + threadIdx.x;
    if (t < n) dst[t] = bfc(src[t]);
}

// ---------------- async global->LDS helper ----------------
typedef const __attribute__((address_space(1))) void gas_void;
typedef __attribute__((address_space(3))) void las_void;
__device__ __forceinline__ void g2l16(const void* g, void* l){
    __builtin_amdgcn_global_load_lds((gas_void*)g, (las_void*)l, 16, 0, 0);
}

// ==================== TIER 1: per-layer kernels (activations in ws) ====================
// TERMINAL configuration (R16/R18, 691-701us verified): hbuf round-trips are
// L3-resident (205MB < 256MB Infinity Cache); unroll-1 keeps VGPR 56 ->
// occupancy 38% (R19 showed full unroll costs occupancy: 245us vs 188us k_f1).

// ---- k_be: BE1+BE2+BE3 fused, 128 edges/block, e3 -> e3buf (bf16 linear) ----
__global__ void __launch_bounds__(512)
k_be(const float* __restrict__ edge_attr,
     const float* __restrict__ b_be1, const float* __restrict__ g_be1, const float* __restrict__ bb_be1,
     const float* __restrict__ b_be2, const float* __restrict__ g_be2, const float* __restrict__ bb_be2,
     const float* __restrict__ b_be3, const float* __restrict__ g_be3, const float* __restrict__ bb_be3,
     const uint16_t* __restrict__ ws, uint16_t* __restrict__ e3buf, int E)
{
    __shared__ char lds[49152];   // bufE 32KB + wb0/wb1 8KB each
    const int t = threadIdx.x, wave = t >> 6, lane = t & 63;
    const int li = lane & 15, lg = lane >> 4;
    const int e0b = blockIdx.x * 128;
    char* bufE = lds;
    uint16_t* wb0 = (uint16_t*)(lds + 32768);
    uint16_t* wb1 = (uint16_t*)(lds + 40960);
    const uint8_t* wsb = (const uint8_t*)ws;

    int cur = 0;
    auto stage8 = [&](int elemoff){
        g2l16(wsb + (size_t)elemoff * 2 + t * 16, (uint8_t*)(cur ? wb0 : wb1) + t * 16);
    };
    auto stepend = [&](){ __syncthreads(); cur ^= 1; };
    auto curb = [&]() -> const uint16_t* { return cur ? wb1 : wb0; };

    f32x4 acc[8];
    auto ldf = [&](int fid) -> bf16x8 { return *(const bf16x8*)(curb() + fid * 512 + lane * 8); };
    auto eb_read = [&](int row, int kt) -> bf16x8 {
        int off = row * 256 + (kt * 32 + lg * 8) * 2;
        return *(const bf16x8*)(bufE + (off ^ ((row & 7) << 4)));
    };
    auto initBE = [&](const float* b){
        #pragma unroll
        for (int ct = 0; ct < 8; ++ct){ float bv = b[li + 16*ct]; f32x4 iv = {bv,bv,bv,bv}; acc[ct] = iv; }
    };
    auto grpBE = [&](bf16x8 a0){
        #pragma unroll
        for (int ct = 0; ct < 8; ++ct)
            acc[ct] = __builtin_amdgcn_mfma_f32_16x16x32_bf16(a0, ldf(ct), acc[ct], 0, 0, 0);
    };
    auto lnstoreBE = [&](const float* g, const float* bb){
        #pragma unroll
        for (int r = 0; r < 4; ++r){
            float s = 0.f, q = 0.f;
            #pragma unroll
            for (int ct = 0; ct < 8; ++ct){ float v = acc[ct][r]; s += v; q += v*v; }
            s += __shfl_xor(s, 1); q += __shfl_xor(q, 1);
            s += __shfl_xor(s, 2); q += __shfl_xor(q, 2);
            s += __shfl_xor(s, 4); q += __shfl_xor(q, 4);
            s += __shfl_xor(s, 8); q += __shfl_xor(q, 8);
            float mu = s * 0.0078125f;
            float var = q * 0.0078125f - mu * mu;
            float rs = rsqrtf(var + 1e-5f);
            int row = wave * 16 + lg * 4 + r;
            int rswz = (row & 7) << 4;
            #pragma unroll
            for (int ct = 0; ct < 8; ++ct){
                int col = li + 16 * ct;
                float v = (acc[ct][r] - mu) * rs * g[col] + bb[col];
                int off = row * 256 + col * 2;
                *(uint16_t*)(bufE + (off ^ rswz)) = bfc(fsilu(v));
            }
        }
    };

    // prologue: BE1 chunk (8KB) -> wb0
    g2l16(wsb + t * 16, (uint8_t*)wb0 + t * 16);
    __syncthreads();

    // BE1 (K=16 pad 32)
    {
        stage8(OFF_BE2);
        initBE(b_be1);
        bf16x8 aE = {0,0,0,0,0,0,0,0};
        if (lg < 2){
            int ea = e0b + wave * 16 + li; if (ea >= E) ea = E - 1;
            const float* pa = edge_attr + (size_t)ea * 16 + lg * 8;
            aE = pack8(*(const float4v*)pa, *(const float4v*)(pa + 4));
        }
        grpBE(aE);
        lnstoreBE(g_be1, bb_be1);
        stepend();
    }
    // BE2
    initBE(b_be2);
    #pragma unroll 1
    for (int kt = 0; kt < 4; ++kt){
        stage8(kt < 3 ? OFF_BE2 + (kt + 1) * 4096 : OFF_BE3);
        grpBE(eb_read(wave * 16 + li, kt));
        if (kt == 3) lnstoreBE(g_be2, bb_be2);
        stepend();
    }
    // BE3
    initBE(b_be3);
    #pragma unroll 1
    for (int kt = 0; kt < 4; ++kt){
        if (kt < 3) stage8(OFF_BE3 + (kt + 1) * 4096);
        grpBE(eb_read(wave * 16 + li, kt));
        if (kt == 3) lnstoreBE(g_be3, bb_be3);
        stepend();                               // last barrier makes e3 visible for copy
    }
    // copy bufE -> e3buf (unswizzle, coalesced 16B)
    #pragma unroll
    for (int i = 0; i < 4; ++i){
        int b = t * 16 + i * 8192;
        int row = b >> 8;
        uint4 v = *(const uint4*)(bufE + (b ^ ((row & 7) << 4)));
        *(uint4*)((uint8_t*)e3buf + (size_t)e0b * 256 + b) = v;
    }
}

// ---- k_d1: 128 -> 256, A from dual_emb f32, out hd1 -> hbuf ----
__global__ void __launch_bounds__(512)
k_d1(const float* __restrict__ dual_emb, const float* __restrict__ b_d1,
     const uint16_t* __restrict__ ws, uint16_t* __restrict__ hbuf, int E)
{
    __shared__ char lds[32768];
    const int t = threadIdx.x, wave = t >> 6, lane = t & 63;
    const int li = lane & 15, lg = lane >> 4;
    const int eg = wave >> 1, ch = wave & 1;
    const int e0b = blockIdx.x * 128;
    uint16_t* wb0 = (uint16_t*)lds;
    uint16_t* wb1 = (uint16_t*)(lds + 16384);
    const uint8_t* wsb = (const uint8_t*)ws;

    int cur = 0;
    auto stage16 = [&](int elemoff){
        uint8_t* dst = (uint8_t*)(cur ? wb0 : wb1) + t * 16;
        const uint8_t* g = wsb + (size_t)elemoff * 2 + t * 16;
        g2l16(g, dst); g2l16(g + 8192, dst + 8192);
    };
    auto stepend = [&](){ __syncthreads(); cur ^= 1; };
    auto curb = [&]() -> const uint16_t* { return cur ? wb1 : wb0; };

    f32x4 acc[2][8];
    #pragma unroll
    for (int ct = 0; ct < 8; ++ct){
        float bv = b_d1[ch * 128 + ct * 16 + li];
        f32x4 iv = {bv, bv, bv, bv};
        acc[0][ct] = iv; acc[1][ct] = iv;
    }

    // prologue: D1 chunk0 (16KB) -> wb0
    {
        const uint8_t* g = wsb + (size_t)OFF_D1 * 2 + t * 16;
        g2l16(g, (uint8_t*)wb0 + t * 16);
        g2l16(g + 8192, (uint8_t*)wb0 + t * 16 + 8192);
    }
    __syncthreads();

    #pragma unroll 1
    for (int kt = 0; kt < 4; ++kt){
        if (kt < 3) stage16(OFF_D1 + (kt + 1) * 8192);
        bf16x8 a0, a1;
        {
            int ea = e0b + eg * 32 + li;      if (ea >= E) ea = E - 1;
            int eb = e0b + eg * 32 + 16 + li; if (eb >= E) eb = E - 1;
            const float* pa = dual_emb + (size_t)ea * 128 + kt * 32 + lg * 8;
            const float* pb = dual_emb + (size_t)eb * 128 + kt * 32 + lg * 8;
            a0 = pack8(*(const float4v*)pa, *(const float4v*)(pa + 4));
            a1 = pack8(*(const float4v*)pb, *(const float4v*)(pb + 4));
        }
        #pragma unroll
        for (int ct = 0; ct < 8; ++ct){
            bf16x8 b = *(const bf16x8*)(curb() + (ch * 8 + ct) * 512 + lane * 8);
            acc[0][ct] = __builtin_amdgcn_mfma_f32_16x16x32_bf16(a0, b, acc[0][ct], 0, 0, 0);
            acc[1][ct] = __builtin_amdgcn_mfma_f32_16x16x32_bf16(a1, b, acc[1][ct], 0, 0, 0);
        }
        if (kt < 3) stepend();
    }
    // silu -> hbuf (linear bf16 [row][256])
    #pragma unroll
    for (int rt = 0; rt < 2; ++rt)
        #pragma unroll
        for (int r = 0; r < 4; ++r){
            size_t row = (size_t)(e0b + eg * 32 + rt * 16 + lg * 4 + r);
            #pragma unroll
            for (int ct = 0; ct < 8; ++ct)
                hbuf[row * 256 + ch * 128 + ct * 16 + li] = bfc(fsilu(acc[rt][ct][r]));
        }
}

// ---- k_d2: 256 -> 256 + W_do dot -> dpbuf ----
__global__ void __launch_bounds__(512)
k_d2(const float* __restrict__ b_d2, const float* __restrict__ W_do, const float* __restrict__ b_do,
     const uint16_t* __restrict__ ws, const uint16_t* __restrict__ hbuf,
     float* __restrict__ dpbuf, int E)
{
    __shared__ char lds[33792];   // wb 32KB + dpp 1KB
    const int t = threadIdx.x, wave = t >> 6, lane = t & 63;
    const int li = lane & 15, lg = lane >> 4;
    const int eg = wave >> 1, ch = wave & 1;
    const int e0b = blockIdx.x * 128;
    uint16_t* wb0 = (uint16_t*)lds;
    uint16_t* wb1 = (uint16_t*)(lds + 16384);
    float* dpp = (float*)(lds + 32768);    // [2][128]
    const uint8_t* wsb = (const uint8_t*)ws;

    int cur = 0;
    auto stage16 = [&](int elemoff){
        uint8_t* dst = (uint8_t*)(cur ? wb0 : wb1) + t * 16;
        const uint8_t* g = wsb + (size_t)elemoff * 2 + t * 16;
        g2l16(g, dst); g2l16(g + 8192, dst + 8192);
    };
    auto stepend = [&](){ __syncthreads(); cur ^= 1; };
    auto curb = [&]() -> const uint16_t* { return cur ? wb1 : wb0; };

    f32x4 acc[2][8];
    #pragma unroll
    for (int ct = 0; ct < 8; ++ct){
        float bv = b_d2[ch * 128 + ct * 16 + li];
        f32x4 iv = {bv, bv, bv, bv};
        acc[0][ct] = iv; acc[1][ct] = iv;
    }
    {
        const uint8_t* g = wsb + (size_t)OFF_D2 * 2 + t * 16;
        g2l16(g, (uint8_t*)wb0 + t * 16);
        g2l16(g + 8192, (uint8_t*)wb0 + t * 16 + 8192);
    }
    __syncthreads();

    #pragma unroll 1
    for (int kt = 0; kt < 8; ++kt){
        if (kt < 7) stage16(OFF_D2 + (kt + 1) * 8192);
        bf16x8 a0 = *(const bf16x8*)(hbuf + (size_t)(e0b + eg * 32 + li) * 256 + kt * 32 + lg * 8);
        bf16x8 a1 = *(const bf16x8*)(hbuf + (size_t)(e0b + eg * 32 + 16 + li) * 256 + kt * 32 + lg * 8);
        #pragma unroll
        for (int ct = 0; ct < 8; ++ct){
            bf16x8 b = *(const bf16x8*)(curb() + (ch * 8 + ct) * 512 + lane * 8);
            acc[0][ct] = __builtin_amdgcn_mfma_f32_16x16x32_bf16(a0, b, acc[0][ct], 0, 0, 0);
            acc[1][ct] = __builtin_amdgcn_mfma_f32_16x16x32_bf16(a1, b, acc[1][ct], 0, 0, 0);
        }
        if (kt < 7) stepend();
    }
    #pragma unroll
    for (int rt = 0; rt < 2; ++rt)
        #pragma unroll
        for (int r = 0; r < 4; ++r){
            float s = 0.f;
            #pragma unroll
            for (int ct = 0; ct < 8; ++ct)
                s += fsilu(acc[rt][ct][r]) * W_do[ch * 128 + ct * 16 + li];
            s += __shfl_xor(s, 1); s += __shfl_xor(s, 2);
            s += __shfl_xor(s, 4); s += __shfl_xor(s, 8);
            if (li == 0) dpp[ch * 128 + eg * 32 + rt * 16 + lg * 4 + r] = s;
        }
    __syncthreads();
    if (t < 128) dpbuf[e0b + t] = fsigmoid(dpp[t] + dpp[128 + t] + b_do[0]);
}

// ---- k_f1: feats(387) -> 256, out x1 -> hbuf (overwrite) ----
__global__ void __launch_bounds__(512)
k_f1(const int* __restrict__ edge_index, const float* __restrict__ logits,
     const float* __restrict__ W_f1, const float* __restrict__ b_f1,
     const uint16_t* __restrict__ ws, const uint16_t* __restrict__ nbf,
     const uint16_t* __restrict__ e3buf, const float* __restrict__ dpbuf,
     uint16_t* __restrict__ hbuf, int E)
{
    __shared__ char lds[34816];   // wb 32KB + ps/pd/sidx/didx 2KB
    const int t = threadIdx.x, wave = t >> 6, lane = t & 63;
    const int li = lane & 15, lg = lane >> 4;
    const int eg = wave >> 1, ch = wave & 1;
    const int e0b = blockIdx.x * 128;
    uint16_t* wb0 = (uint16_t*)lds;
    uint16_t* wb1 = (uint16_t*)(lds + 16384);
    float* ps = (float*)(lds + 32768);
    float* pd = (float*)(lds + 33280);
    int* sidx = (int*)(lds + 33792);
    int* didx = (int*)(lds + 34304);
    const uint8_t* wsb = (const uint8_t*)ws;

    if (t < 128) {
        int e = e0b + t; if (e >= E) e = E - 1;
        int s_ = edge_index[e];
        int d_ = edge_index[E + e];
        sidx[t] = s_; didx[t] = d_;
        ps[t] = fsigmoid(logits[s_]);
        pd[t] = fsigmoid(logits[d_]);
    }
    int cur = 0;
    auto stage16 = [&](int elemoff){
        uint8_t* dst = (uint8_t*)(cur ? wb0 : wb1) + t * 16;
        const uint8_t* g = wsb + (size_t)elemoff * 2 + t * 16;
        g2l16(g, dst); g2l16(g + 8192, dst + 8192);
    };
    auto stepend = [&](){ __syncthreads(); cur ^= 1; };
    auto curb = [&]() -> const uint16_t* { return cur ? wb1 : wb0; };

    {
        const uint8_t* g = wsb + (size_t)OFF_F1 * 2 + t * 16;
        g2l16(g, (uint8_t*)wb0 + t * 16);
        g2l16(g + 8192, (uint8_t*)wb0 + t * 16 + 8192);
    }
    __syncthreads();    // also makes ps/pd/sidx/didx visible

    f32x4 acc[2][8];
    {
        #pragma unroll
        for (int ct = 0; ct < 8; ++ct){
            int col = ch * 128 + ct * 16 + li;
            float bv = b_f1[col];
            float t0 = W_f1[384 * 256 + col];
            float t1 = W_f1[385 * 256 + col];
            float t2 = W_f1[386 * 256 + col];
            #pragma unroll
            for (int rt = 0; rt < 2; ++rt)
                #pragma unroll
                for (int r = 0; r < 4; ++r){
                    int row = eg * 32 + rt * 16 + lg * 4 + r;
                    float dv = dpbuf[e0b + row];
                    acc[rt][ct][r] = bv + dv*t0 + ps[row]*t1 + pd[row]*t2;
                }
        }
    }
    int s0 = sidx[eg * 32 + li],  s1 = sidx[eg * 32 + 16 + li];
    int d0 = didx[eg * 32 + li],  d1 = didx[eg * 32 + 16 + li];
    #pragma unroll 1
    for (int kt = 0; kt < 12; ++kt){
        if (kt < 11) stage16(OFF_F1 + (kt + 1) * 8192);
        bf16x8 a0, a1;
        if (kt < 8){
            int ra = (kt < 4) ? s0 : d0;
            int rb = (kt < 4) ? s1 : d1;
            int ko = (kt & 3) * 32 + lg * 8;
            a0 = *(const bf16x8*)(nbf + (size_t)ra * 128 + ko);
            a1 = *(const bf16x8*)(nbf + (size_t)rb * 128 + ko);
        } else {
            int ko = (kt - 8) * 32 + lg * 8;
            a0 = *(const bf16x8*)(e3buf + (size_t)(e0b + eg * 32 + li) * 128 + ko);
            a1 = *(const bf16x8*)(e3buf + (size_t)(e0b + eg * 32 + 16 + li) * 128 + ko);
        }
        #pragma unroll
        for (int ct = 0; ct < 8; ++ct){
            bf16x8 b = *(const bf16x8*)(curb() + (ch * 8 + ct) * 512 + lane * 8);
            acc[0][ct] = __builtin_amdgcn_mfma_f32_16x16x32_bf16(a0, b, acc[0][ct], 0, 0, 0);
            acc[1][ct] = __builtin_amdgcn_mfma_f32_16x16x32_bf16(a1, b, acc[1][ct], 0, 0, 0);
        }
        if (kt < 11) stepend();
    }
    #pragma unroll
    for (int rt = 0; rt < 2; ++rt)
        #pragma unroll
        for (int r = 0; r < 4; ++r){
            size_t row = (size_t)(e0b + eg * 32 + rt * 16 + lg * 4 + r);
            #pragma unroll
            for (int ct = 0; ct < 8; ++ct)
                hbuf[row * 256 + ch * 128 + ct * 16 + li] = bfc(fsilu(acc[rt][ct][r]));
        }
}

// ---- k_f2: 256 -> 256 + W_bo dot -> out ----
__global__ void __launch_bounds__(512)
k_f2(const float* __restrict__ b_f2, const float* __restrict__ W_bo, const float* __restrict__ b_bo,
     const uint16_t* __restrict__ ws, const uint16_t* __restrict__ hbuf,
     float* __restrict__ out, int E)
{
    __shared__ char lds[33792];
    const int t = threadIdx.x, wave = t >> 6, lane = t & 63;
    const int li = lane & 15, lg = lane >> 4;
    const int eg = wave >> 1, ch = wave & 1;
    const int e0b = blockIdx.x * 128;
    uint16_t* wb0 = (uint16_t*)lds;
    uint16_t* wb1 = (uint16_t*)(lds + 16384);
    float* bop = (float*)(lds + 32768);
    const uint8_t* wsb = (const uint8_t*)ws;

    int cur = 0;
    auto stage16 = [&](int elemoff){
        uint8_t* dst = (uint8_t*)(cur ? wb0 : wb1) + t * 16;
        const uint8_t* g = wsb + (size_t)elemoff * 2 + t * 16;
        g2l16(g, dst); g2l16(g + 8192, dst + 8192);
    };
    auto stepend = [&](){ __syncthreads(); cur ^= 1; };
    auto curb = [&]() -> const uint16_t* { return cur ? wb1 : wb0; };

    f32x4 acc[2][8];
    #pragma unroll
    for (int ct = 0; ct < 8; ++ct){
        float bv = b_f2[ch * 128 + ct * 16 + li];
        f32x4 iv = {bv, bv, bv, bv};
        acc[0][ct] = iv; acc[1][ct] = iv;
    }
    {
        const uint8_t* g = wsb + (size_t)OFF_F2 * 2 + t * 16;
        g2l16(g, (uint8_t*)wb0 + t * 16);
        g2l16(g + 8192, (uint8_t*)wb0 + t * 16 + 8192);
    }
    __syncthreads();

    #pragma unroll 1
    for (int kt = 0; kt < 8; ++kt){
        if (kt < 7) stage16(OFF_F2 + (kt + 1) * 8192);
        bf16x8 a0 = *(const bf16x8*)(hbuf + (size_t)(e0b + eg * 32 + li) * 256 + kt * 32 + lg * 8);
        bf16x8 a1 = *(const bf16x8*)(hbuf + (size_t)(e0b + eg * 32 + 16 + li) * 256 + kt * 32 + lg * 8);
        #pragma unroll
        for (int ct = 0; ct < 8; ++ct){
            bf16x8 b = *(const bf16x8*)(curb() + (ch * 8 + ct) * 512 + lane * 8);
            acc[0][ct] = __builtin_amdgcn_mfma_f32_16x16x32_bf16(a0, b, acc[0][ct], 0, 0, 0);
            acc[1][ct] = __builtin_amdgcn_mfma_f32_16x16x32_bf16(a1, b, acc[1][ct], 0, 0, 0);
        }
        if (kt < 7) stepend();
    }
    #pragma unroll
    for (int rt = 0; rt < 2; ++rt)
        #pragma unroll
        for (int r = 0; r < 4; ++r){
            float s = 0.f;
            #pragma unroll
            for (int ct = 0; ct < 8; ++ct)
                s += fsilu(acc[rt][ct][r]) * W_bo[ch * 128 + ct * 16 + li];
            s += __shfl_xor(s, 1); s += __shfl_xor(s, 2);
            s += __shfl_xor(s, 4); s += __shfl_xor(s, 8);
            if (li == 0) bop[ch * 128 + eg * 32 + rt * 16 + lg * 4 + r] = s;
        }
    __syncthreads();
    if (t < 128){
        int e = e0b + t;
        if (e < E) out[e] = bop[t] + bop[128 + t] + b_bo[0];
    }
}

// ==================== TIER 2: R10 megakernel (verified 709us) ====================
#define LDS_TOTAL 135168
__global__ void __launch_bounds__(512) __attribute__((amdgpu_waves_per_eu(2, 2)))
bond_fast_kernel(const int* __restrict__ edge_index,
                 const float* __restrict__ edge_attr, const float* __restrict__ dual_emb,
                 const float* __restrict__ logits,
                 const float* __restrict__ b_be1, const float* __restrict__ g_be1, const float* __restrict__ bb_be1,
                 const float* __restrict__ b_be2, const float* __restrict__ g_be2, const float* __restrict__ bb_be2,
                 const float* __restrict__ b_be3, const float* __restrict__ g_be3, const float* __restrict__ bb_be3,
                 const float* __restrict__ b_d1, const float* __restrict__ b_d2,
                 const float* __restrict__ W_do, const float* __restrict__ b_do,
                 const float* __restrict__ W_f1, const float* __restrict__ b_f1,
                 const float* __restrict__ b_f2,
                 const float* __restrict__ W_bo, const float* __restrict__ b_bo,
                 const uint16_t* __restrict__ ws, float* __restrict__ out, int E)
{
    __shared__ char lds[LDS_TOTAL];
    const int t    = threadIdx.x;
    const int wave = t >> 6;
    const int lane = t & 63;
    const int li   = lane & 15, lg = lane >> 4;
    const int eg   = wave >> 1;
    const int ch   = wave & 1;
    const int e0b  = blockIdx.x * 128;

    char* bufE = lds;
    char* h256 = lds + 32768;
    uint16_t* wb0 = (uint16_t*)(lds + 98304);
    uint16_t* wb1 = (uint16_t*)(lds + 114688);
    float* ps  = (float*)(lds + 131072);
    float* pd  = (float*)(lds + 131584);
    int* sidx  = (int*)(lds + 132096);
    int* didx  = (int*)(lds + 132608);
    float* dpp = (float*)(lds + 133120);
    float* bop = (float*)(lds + 134144);

    const uint8_t*  wsb = (const uint8_t*)ws;
    const uint16_t* nbf = ws + WS_ELEMS;

    if (t < 128) {
        int e = e0b + t; if (e >= E) e = E - 1;
        int s_ = edge_index[e];
        int d_ = edge_index[E + e];
        sidx[t] = s_; didx[t] = d_;
        ps[t] = fsigmoid(logits[s_]);
        pd[t] = fsigmoid(logits[d_]);
    }

    int cur = 0;
    auto stageW = [&](int elemoff, int big){
        uint8_t* dst = (uint8_t*)(cur ? wb0 : wb1) + t * 16;
        const uint8_t* g = wsb + (size_t)elemoff * 2 + t * 16;
        g2l16(g, dst);
        if (big) g2l16(g + 8192, dst + 8192);
    };
    auto stepend = [&](){ __syncthreads(); cur ^= 1; };
    auto curbuf  = [&]() -> const uint16_t* { return cur ? wb1 : wb0; };

    f32x4 acc[2][8];

    auto ldf = [&](const uint16_t* w, int fid) -> bf16x8 {
        return *(const bf16x8*)(w + fid * 512 + lane * 8);
    };
    auto grpBE = [&](const uint16_t* w, bf16x8 a0){
        #pragma unroll
        for (int ct = 0; ct < 8; ++ct){
            bf16x8 b = ldf(w, ct);
            acc[0][ct] = __builtin_amdgcn_mfma_f32_16x16x32_bf16(a0, b, acc[0][ct], 0, 0, 0);
        }
    };
    auto grp256 = [&](const uint16_t* w, bf16x8 a0, bf16x8 a1){
        #pragma unroll
        for (int ct = 0; ct < 8; ++ct){
            bf16x8 b = ldf(w, ch * 8 + ct);
            acc[0][ct] = __builtin_amdgcn_mfma_f32_16x16x32_bf16(a0, b, acc[0][ct], 0, 0, 0);
            acc[1][ct] = __builtin_amdgcn_mfma_f32_16x16x32_bf16(a1, b, acc[1][ct], 0, 0, 0);
        }
    };
    auto initBE = [&](const float* b){
        #pragma unroll
        for (int ct = 0; ct < 8; ++ct){
            float bv = b[li + 16 * ct];
            f32x4 iv = {bv, bv, bv, bv};
            acc[0][ct] = iv;
        }
    };
    auto init256 = [&](const float* b){
        #pragma unroll
        for (int ct = 0; ct < 8; ++ct){
            float bv = b[ch * 128 + ct * 16 + li];
            f32x4 iv = {bv, bv, bv, bv};
            acc[0][ct] = iv; acc[1][ct] = iv;
        }
    };
    auto eb_read = [&](int row, int kt) -> bf16x8 {
        int off = row * 256 + (kt * 32 + lg * 8) * 2;
        return *(const bf16x8*)(bufE + (off ^ ((row & 7) << 4)));
    };
    auto h2_read = [&](int row, int kt) -> bf16x8 {
        int off = row * 512 + (kt * 32 + lg * 8) * 2;
        return *(const bf16x8*)(h256 + (off ^ ((row & 7) << 4)));
    };
    auto lnstoreBE = [&](const float* g, const float* bb){
        #pragma unroll
        for (int r = 0; r < 4; ++r){
            float s = 0.f, q = 0.f;
            #pragma unroll
            for (int ct = 0; ct < 8; ++ct){ float v = acc[0][ct][r]; s += v; q += v*v; }
            s += __shfl_xor(s, 1); q += __shfl_xor(q, 1);
            s += __shfl_xor(s, 2); q += __shfl_xor(q, 2);
            s += __shfl_xor(s, 4); q += __shfl_xor(q, 4);
            s += __shfl_xor(s, 8); q += __shfl_xor(q, 8);
            float mu = s * 0.0078125f;
            float var = q * 0.0078125f - mu * mu;
            float rs = rsqrtf(var + 1e-5f);
            int row = wave * 16 + lg * 4 + r;
            int rswz = (row & 7) << 4;
            #pragma unroll
            for (int ct = 0; ct < 8; ++ct){
                int col = li + 16 * ct;
                float v = (acc[0][ct][r] - mu) * rs * g[col] + bb[col];
                int off = row * 256 + col * 2;
                *(uint16_t*)(bufE + (off ^ rswz)) = bfc(fsilu(v));
            }
        }
    };
    auto silustore256 = [&](){
        #pragma unroll
        for (int rt = 0; rt < 2; ++rt){
            #pragma unroll
            for (int r = 0; r < 4; ++r){
                int row = eg * 32 + rt * 16 + lg * 4 + r;
                int rswz = (row & 7) << 4;
                #pragma unroll
                for (int ct = 0; ct < 8; ++ct){
                    int off = row * 512 + (ch * 128 + ct * 16 + li) * 2;
                    *(uint16_t*)(h256 + (off ^ rswz)) = bfc(fsilu(acc[rt][ct][r]));
                }
            }
        }
    };

    {
        const uint8_t* g = wsb + t * 16;
        g2l16(g, (uint8_t*)wb0 + t * 16);
    }
    __syncthreads();

    {
        stageW(OFF_BE2, 0);
        bf16x8 aE = {0,0,0,0,0,0,0,0};
        if (lg < 2){
            int ea = e0b + wave * 16 + li; if (ea >= E) ea = E - 1;
            const float* pa = edge_attr + (size_t)ea * 16 + lg * 8;
            aE = pack8(*(const float4v*)pa, *(const float4v*)(pa + 4));
        }
        initBE(b_be1);
        grpBE(curbuf(), aE);
        lnstoreBE(g_be1, bb_be1);
        stepend();
    }

    initBE(b_be2);
    #pragma unroll
    for (int kt = 0; kt < 4; ++kt){
        if (kt < 3) stageW(OFF_BE2 + (kt + 1) * 4096, 0);
        else        stageW(OFF_BE3, 0);
        grpBE(curbuf(), eb_read(wave * 16 + li, kt));
        if (kt == 3) lnstoreBE(g_be2, bb_be2);
        stepend();
    }
    initBE(b_be3);
    #pragma unroll
    for (int kt = 0; kt < 4; ++kt){
        if (kt < 3) stageW(OFF_BE3 + (kt + 1) * 4096, 0);
        else        stageW(OFF_D1, 1);
        grpBE(curbuf(), eb_read(wave * 16 + li, kt));
        if (kt == 3) lnstoreBE(g_be3, bb_be3);
        stepend();
    }

    init256(b_d1);
    #pragma unroll
    for (int kt = 0; kt < 4; ++kt){
        float4v va0, va1, vb0, vb1;
        {
            int ea = e0b + eg * 32 + li;      if (ea >= E) ea = E - 1;
            int eb = e0b + eg * 32 + 16 + li; if (eb >= E) eb = E - 1;
            const float* pa = dual_emb + (size_t)ea * 128 + kt * 32 + lg * 8;
            const float* pb = dual_emb + (size_t)eb * 128 + kt * 32 + lg * 8;
            va0 = *(const float4v*)pa; va1 = *(const float4v*)(pa + 4);
            vb0 = *(const float4v*)pb; vb1 = *(const float4v*)(pb + 4);
        }
        if (kt < 3) stageW(OFF_D1 + (kt + 1) * 8192, 1);
        else        stageW(OFF_D2, 1);
        grp256(curbuf(), pack8(va0, va1), pack8(vb0, vb1));
        if (kt == 3) silustore256();
        stepend();
    }

    init256(b_d2);
    #pragma unroll
    for (int kt = 0; kt < 8; ++kt){
        if (kt < 7) stageW(OFF_D2 + (kt + 1) * 8192, 1);
        else        stageW(OFF_F1, 1);
        grp256(curbuf(), h2_read(eg * 32 + li, kt), h2_read(eg * 32 + 16 + li, kt));
        if (kt == 7){
            #pragma unroll
            for (int rt = 0; rt < 2; ++rt){
                #pragma unroll
                for (int r = 0; r < 4; ++r){
                    float s = 0.f;
                    #pragma unroll
                    for (int ct = 0; ct < 8; ++ct)
                        s += fsilu(acc[rt][ct][r]) * W_do[ch * 128 + ct * 16 + li];
                    s += __shfl_xor(s, 1); s += __shfl_xor(s, 2);
                    s += __shfl_xor(s, 4); s += __shfl_xor(s, 8);
                    if (li == 0) dpp[ch * 128 + eg * 32 + rt * 16 + lg * 4 + r] = s;
                }
            }
        }
        stepend();
    }

    {
        {
            float bdo0 = b_do[0];
            #pragma unroll
            for (int ct = 0; ct < 8; ++ct){
                int col = ch * 128 + ct * 16 + li;
                float bv = b_f1[col];
                float t0 = W_f1[384 * 256 + col];
                float t1 = W_f1[385 * 256 + col];
                float t2 = W_f1[386 * 256 + col];
                #pragma unroll
                for (int rt = 0; rt < 2; ++rt)
                    #pragma unroll
                    for (int r = 0; r < 4; ++r){
                        int row = eg * 32 + rt * 16 + lg * 4 + r;
                        float dv = fsigmoid(dpp[row] + dpp[128 + row] + bdo0);
                        acc[rt][ct][r] = bv + dv*t0 + ps[row]*t1 + pd[row]*t2;
                    }
            }
        }
        int s0 = sidx[eg * 32 + li],      s1 = sidx[eg * 32 + 16 + li];
        int d0 = didx[eg * 32 + li],      d1 = didx[eg * 32 + 16 + li];
        #pragma unroll
        for (int kt = 0; kt < 12; ++kt){
            bf16x8 a0, a1;
            if (kt < 8){
                int ra = (kt < 4) ? s0 : d0;
                int rb = (kt < 4) ? s1 : d1;
                int ko = (kt & 3) * 32 + lg * 8;
                a0 = *(const bf16x8*)(nbf + (size_t)ra * 128 + ko);
                a1 = *(const bf16x8*)(nbf + (size_t)rb * 128 + ko);
            } else {
                a0 = eb_read(eg * 32 + li, kt - 8);
                a1 = eb_read(eg * 32 + 16 + li, kt - 8);
            }
            if (kt < 11) stageW(OFF_F1 + (kt + 1) * 8192, 1);
            else         stageW(OFF_F2, 1);
            grp256(curbuf(), a0, a1);
            if (kt == 11) silustore256();
            stepend();
        }
    }

    init256(b_f2);
    #pragma unroll
    for (int kt = 0; kt < 8; ++kt){
        if (kt < 7) stageW(OFF_F2 + (kt + 1) * 8192, 1);
        grp256(curbuf(), h2_read(eg * 32 + li, kt), h2_read(eg * 32 + 16 + li, kt));
        if (kt == 7){
            #pragma unroll
            for (int rt = 0; rt < 2; ++rt){
                #pragma unroll
                for (int r = 0; r < 4; ++r){
                    float s = 0.f;
                    #pragma unroll
                    for (int ct = 0; ct < 8; ++ct)
                        s += fsilu(acc[rt][ct][r]) * W_bo[ch * 128 + ct * 16 + li];
                    s += __shfl_xor(s, 1); s += __shfl_xor(s, 2);
                    s += __shfl_xor(s, 4); s += __shfl_xor(s, 8);
                    if (li == 0) bop[ch * 128 + eg * 32 + rt * 16 + lg * 4 + r] = s;
                }
            }
        } else {
            stepend();
        }
    }
    __syncthreads();
    if (t < 128){
        int e = e0b + t;
        if (e < E) out[e] = bop[t] + bop[128 + t] + b_bo[0];
    }
}

// ==================== TIER 3: R6 self-contained fallback (no ws) ====================
__global__ void __launch_bounds__(512) __attribute__((amdgpu_waves_per_eu(2, 2)))
bond_fused_kernel(const float* __restrict__ node_emb, const int* __restrict__ edge_index,
                  const float* __restrict__ edge_attr, const float* __restrict__ dual_emb,
                  const float* __restrict__ logits,
                  const float* __restrict__ W_be1, const float* __restrict__ b_be1,
                  const float* __restrict__ g_be1, const float* __restrict__ bb_be1,
                  const float* __restrict__ W_be2, const float* __restrict__ b_be2,
                  const float* __restrict__ g_be2, const float* __restrict__ bb_be2,
                  const float* __restrict__ W_be3, const float* __restrict__ b_be3,
                  const float* __restrict__ g_be3, const float* __restrict__ bb_be3,
                  const float* __restrict__ W_d1, const float* __restrict__ b_d1,
                  const float* __restrict__ W_d2, const float* __restrict__ b_d2,
                  const float* __restrict__ W_do, const float* __restrict__ b_do,
                  const float* __restrict__ W_f1, const float* __restrict__ b_f1,
                  const float* __restrict__ W_f2, const float* __restrict__ b_f2,
                  const float* __restrict__ W_bo, const float* __restrict__ b_bo,
                  float* __restrict__ out, int E)
{
    __shared__ char lds[LDS_TOTAL];
    const int t    = threadIdx.x;
    const int wave = t >> 6;
    const int lane = t & 63;
    const int li   = lane & 15, lg = lane >> 4;
    const int eg   = wave >> 1;
    const int ch   = wave & 1;
    const int e0b  = blockIdx.x * 128;

    char* bufE = lds;
    char* h256 = lds + 32768;
    uint16_t* wb0 = (uint16_t*)(lds + 98304);
    uint16_t* wb1 = (uint16_t*)(lds + 114688);
    float* ps  = (float*)(lds + 131072);
    float* pd  = (float*)(lds + 131584);
    int* sidx  = (int*)(lds + 132096);
    int* didx  = (int*)(lds + 132608);
    float* dpp = (float*)(lds + 133120);
    float* bop = (float*)(lds + 134144);

    if (t < 128) {
        int e = e0b + t; if (e >= E) e = E - 1;
        int s_ = edge_index[e];
        int d_ = edge_index[E + e];
        sidx[t] = s_; didx[t] = d_;
        ps[t] = fsigmoid(logits[s_]);
        pd[t] = fsigmoid(logits[d_]);
    }

    float sr[2][8];
    auto issueW256 = [&](const float* W, int kbase){
        #pragma unroll
        for (int h = 0; h < 2; ++h){
            const float* p = W + (size_t)(kbase + lg * 8) * 256 + (wave + 8*h) * 16 + li;
            #pragma unroll
            for (int j = 0; j < 8; ++j) sr[h][j] = p[j * 256];
        }
    };
    auto issueW128 = [&](const float* W, int kbase, int K){
        const float* p = W + (size_t)(kbase + lg * 8) * 128 + wave * 16 + li;
        #pragma unroll
        for (int j = 0; j < 8; ++j)
            sr[0][j] = (kbase + lg * 8 + j < K) ? p[j * 128] : 0.f;
    };
    auto commitW = [&](uint16_t* dst, int nh){
        #pragma unroll
        for (int h = 0; h < 2; ++h){
            if (h < nh){
                uint4 w;
                w.x = pk2(sr[h][0], sr[h][1]); w.y = pk2(sr[h][2], sr[h][3]);
                w.z = pk2(sr[h][4], sr[h][5]); w.w = pk2(sr[h][6], sr[h][7]);
                *(uint4*)(dst + (wave + 8*h) * 512 + lane * 8) = w;
            }
        }
    };

    int cur = 0;
    auto stepend = [&](int mode){
        if (mode) commitW(cur ? wb0 : wb1, mode == 128 ? 1 : 2);
        __syncthreads();
        cur ^= 1;
    };
    auto curbuf = [&]() -> const uint16_t* { return cur ? wb1 : wb0; };

    f32x4 acc[2][8];

    auto ldf = [&](const uint16_t* w, int fid) -> bf16x8 {
        return *(const bf16x8*)(w + fid * 512 + lane * 8);
    };
    auto grpBE = [&](const uint16_t* w, bf16x8 a0){
        #pragma unroll
        for (int ct = 0; ct < 8; ++ct){
            bf16x8 b = ldf(w, ct);
            acc[0][ct] = __builtin_amdgcn_mfma_f32_16x16x32_bf16(a0, b, acc[0][ct], 0, 0, 0);
        }
    };
    auto grp256 = [&](const uint16_t* w, bf16x8 a0, bf16x8 a1){
        #pragma unroll
        for (int ct = 0; ct < 8; ++ct){
            bf16x8 b = ldf(w, ch * 8 + ct);
            acc[0][ct] = __builtin_amdgcn_mfma_f32_16x16x32_bf16(a0, b, acc[0][ct], 0, 0, 0);
            acc[1][ct] = __builtin_amdgcn_mfma_f32_16x16x32_bf16(a1, b, acc[1][ct], 0, 0, 0);
        }
    };
    auto initBE = [&](const float* b){
        #pragma unroll
        for (int ct = 0; ct < 8; ++ct){
            float bv = b[li + 16 * ct];
            f32x4 iv = {bv, bv, bv, bv};
            acc[0][ct] = iv;
        }
    };
    auto init256 = [&](const float* b){
        #pragma unroll
        for (int ct = 0; ct < 8; ++ct){
            float bv = b[ch * 128 + ct * 16 + li];
            f32x4 iv = {bv, bv, bv, bv};
            acc[0][ct] = iv; acc[1][ct] = iv;
        }
    };
    auto eb_read = [&](int row, int kt) -> bf16x8 {
        int off = row * 256 + (kt * 32 + lg * 8) * 2;
        return *(const bf16x8*)(bufE + (off ^ ((row & 7) << 4)));
    };
    auto h2_read = [&](int row, int kt) -> bf16x8 {
        int off = row * 512 + (kt * 32 + lg * 8) * 2;
        return *(const bf16x8*)(h256 + (off ^ ((row & 7) << 4)));
    };
    auto lnstoreBE = [&](const float* g, const float* bb){
        #pragma unroll
        for (int r = 0; r < 4; ++r){
            float s = 0.f, q = 0.f;
            #pragma unroll
            for (int ct = 0; ct < 8; ++ct){ float v = acc[0][ct][r]; s += v; q += v*v; }
            s += __shfl_xor(s, 1); q += __shfl_xor(q, 1);
            s += __shfl_xor(s, 2); q += __shfl_xor(q, 2);
            s += __shfl_xor(s, 4); q += __shfl_xor(q, 4);
            s += __shfl_xor(s, 8); q += __shfl_xor(q, 8);
            float mu = s * 0.0078125f;
            float var = q * 0.0078125f - mu * mu;
            float rs = rsqrtf(var + 1e-5f);
            int row = wave * 16 + lg * 4 + r;
            int rswz = (row & 7) << 4;
            #pragma unroll
            for (int ct = 0; ct < 8; ++ct){
                int col = li + 16 * ct;
                float v = (acc[0][ct][r] - mu) * rs * g[col] + bb[col];
                int off = row * 256 + col * 2;
                *(uint16_t*)(bufE + (off ^ rswz)) = bfc(fsilu(v));
            }
        }
    };
    auto silustore256 = [&](){
        #pragma unroll
        for (int rt = 0; rt < 2; ++rt){
            #pragma unroll
            for (int r = 0; r < 4; ++r){
                int row = eg * 32 + rt * 16 + lg * 4 + r;
                int rswz = (row & 7) << 4;
                #pragma unroll
                for (int ct = 0; ct < 8; ++ct){
                    int off = row * 512 + (ch * 128 + ct * 16 + li) * 2;
                    *(uint16_t*)(h256 + (off ^ rswz)) = bfc(fsilu(acc[rt][ct][r]));
                }
            }
        }
    };

    issueW128(W_be1, 0, 16);
    commitW(wb0, 1);
    __syncthreads();

    {
        bf16x8 aE = {0,0,0,0,0,0,0,0};
        if (lg < 2){
            int ea = e0b + wave * 16 + li; if (ea >= E) ea = E - 1;
            const float* pa = edge_attr + (size_t)ea * 16 + lg * 8;
            aE = pack8(*(const float4v*)pa, *(const float4v*)(pa + 4));
        }
        issueW128(W_be2, 0, 128);
        initBE(b_be1);
        grpBE(curbuf(), aE);
        lnstoreBE(g_be1, bb_be1);
        stepend(128);
    }

    initBE(b_be2);
    #pragma unroll 1
    for (int kt = 0; kt < 4; ++kt){
        if (kt < 3) issueW128(W_be2, (kt + 1) * 32, 128);
        else        issueW128(W_be3, 0, 128);
        grpBE(curbuf(), eb_read(wave * 16 + li, kt));
        if (kt == 3) lnstoreBE(g_be2, bb_be2);
        stepend(128);
    }
    initBE(b_be3);
    #pragma unroll 1
    for (int kt = 0; kt < 4; ++kt){
        if (kt < 3) issueW128(W_be3, (kt + 1) * 32, 128);
        else        issueW256(W_d1, 0);
        grpBE(curbuf(), eb_read(wave * 16 + li, kt));
        if (kt == 3) lnstoreBE(g_be3, bb_be3);
        stepend(kt < 3 ? 128 : 256);
    }

    init256(b_d1);
    #pragma unroll 1
    for (int kt = 0; kt < 4; ++kt){
        float4v va0, va1, vb0, vb1;
        {
            int ea = e0b + eg * 32 + li;      if (ea >= E) ea = E - 1;
            int eb = e0b + eg * 32 + 16 + li; if (eb >= E) eb = E - 1;
            const float* pa = dual_emb + (size_t)ea * 128 + kt * 32 + lg * 8;
            const float* pb = dual_emb + (size_t)eb * 128 + kt * 32 + lg * 8;
            va0 = *(const float4v*)pa; va1 = *(const float4v*)(pa + 4);
            vb0 = *(const float4v*)pb; vb1 = *(const float4v*)(pb + 4);
        }
        if (kt < 3) issueW256(W_d1, (kt + 1) * 32);
        else        issueW256(W_d2, 0);
        grp256(curbuf(), pack8(va0, va1), pack8(vb0, vb1));
        if (kt == 3) silustore256();
        stepend(256);
    }

    init256(b_d2);
    #pragma unroll 1
    for (int kt = 0; kt < 8; ++kt){
        if (kt < 7) issueW256(W_d2, (kt + 1) * 32);
        else        issueW256(W_f1, 0);
        grp256(curbuf(), h2_read(eg * 32 + li, kt), h2_read(eg * 32 + 16 + li, kt));
        if (kt == 7){
            #pragma unroll
            for (int rt = 0; rt < 2; ++rt){
                #pragma unroll
                for (int r = 0; r < 4; ++r){
                    float s = 0.f;
                    #pragma unroll
                    for (int ct = 0; ct < 8; ++ct)
                        s += fsilu(acc[rt][ct][r]) * W_do[ch * 128 + ct * 16 + li];
                    s += __shfl_xor(s, 1); s += __shfl_xor(s, 2);
                    s += __shfl_xor(s, 4); s += __shfl_xor(s, 8);
                    if (li == 0) dpp[ch * 128 + eg * 32 + rt * 16 + lg * 4 + r] = s;
                }
            }
        }
        stepend(256);
    }

    {
        {
            float bdo0 = b_do[0];
            #pragma unroll
            for (int ct = 0; ct < 8; ++ct){
                int col = ch * 128 + ct * 16 + li;
                float bv = b_f1[col];
                float t0 = W_f1[384 * 256 + col];
                float t1 = W_f1[385 * 256 + col];
                float t2 = W_f1[386 * 256 + col];
                #pragma unroll
                for (int rt = 0; rt < 2; ++rt)
                    #pragma unroll
                    for (int r = 0; r < 4; ++r){
                        int row = eg * 32 + rt * 16 + lg * 4 + r;
                        float dv = fsigmoid(dpp[row] + dpp[128 + row] + bdo0);
                        acc[rt][ct][r] = bv + dv*t0 + ps[row]*t1 + pd[row]*t2;
                    }
            }
        }
        int s0 = sidx[eg * 32 + li],      s1 = sidx[eg * 32 + 16 + li];
        int d0 = didx[eg * 32 + li],      d1 = didx[eg * 32 + 16 + li];
        #pragma unroll 1
        for (int kt = 0; kt < 12; ++kt){
            bf16x8 a0, a1;
            if (kt < 8){
                int ra = (kt < 4) ? s0 : d0;
                int rb = (kt < 4) ? s1 : d1;
                int ko = (kt & 3) * 32 + lg * 8;
                const float* pa = node_emb + (size_t)ra * 128 + ko;
                const float* pb = node_emb + (size_t)rb * 128 + ko;
                a0 = pack8(*(const float4v*)pa, *(const float4v*)(pa + 4));
                a1 = pack8(*(const float4v*)pb, *(const float4v*)(pb + 4));
            } else {
                a0 = eb_read(eg * 32 + li, kt - 8);
                a1 = eb_read(eg * 32 + 16 + li, kt - 8);
            }
            if (kt < 11) issueW256(W_f1, (kt + 1) * 32);
            else         issueW256(W_f2, 0);
            grp256(curbuf(), a0, a1);
            if (kt == 11) silustore256();
            stepend(256);
        }
    }

    init256(b_f2);
    #pragma unroll 1
    for (int kt = 0; kt < 8; ++kt){
        if (kt < 7) issueW256(W_f2, (kt + 1) * 32);
        grp256(curbuf(), h2_read(eg * 32 + li, kt), h2_read(eg * 32 + 16 + li, kt));
        if (kt == 7){
            #pragma unroll
            for (int rt = 0; rt < 2; ++rt){
                #pragma unroll
                for (int r = 0; r < 4; ++r){
                    float s = 0.f;
                    #pragma unroll
                    for (int ct = 0; ct < 8; ++ct)
                        s += fsilu(acc[rt][ct][r]) * W_bo[ch * 128 + ct * 16 + li];
                    s += __shfl_xor(s, 1); s += __shfl_xor(s, 2);
                    s += __shfl_xor(s, 4); s += __shfl_xor(s, 8);
                    if (li == 0) bop[ch * 128 + eg * 32 + rt * 16 + lg * 4 + r] = s;
                }
            }
        } else {
            stepend(256);
        }
    }
    __syncthreads();
    if (t < 128){
        int e = e0b + t;
        if (e < E) out[e] = bop[t] + bop[128 + t] + b_bo[0];
    }
}

extern "C" void kernel_launch(void* const* d_in, const int* in_sizes, int n_in,
                              void* d_out, int out_size, void* d_ws, size_t ws_size,
                              hipStream_t stream) {
    const float* node_emb   = (const float*)d_in[0];
    const int*   edge_index = (const int*)d_in[1];
    const float* edge_attr  = (const float*)d_in[2];
    const float* dual_emb   = (const float*)d_in[3];
    const float* logits     = (const float*)d_in[4];
    const float* W_be1 = (const float*)d_in[5];
    const float* b_be1 = (const float*)d_in[6];
    const float* g_be1 = (const float*)d_in[7];
    const float* bb_be1= (const float*)d_in[8];
    const float* W_be2 = (const float*)d_in[9];
    const float* b_be2 = (const float*)d_in[10];
    const float* g_be2 = (const float*)d_in[11];
    const float* bb_be2= (const float*)d_in[12];
    const float* W_be3 = (const float*)d_in[13];
    const float* b_be3 = (const float*)d_in[14];
    const float* g_be3 = (const float*)d_in[15];
    const float* bb_be3= (const float*)d_in[16];
    const float* W_d1  = (const float*)d_in[17];
    const float* b_d1  = (const float*)d_in[18];
    const float* W_d2  = (const float*)d_in[19];
    const float* b_d2  = (const float*)d_in[20];
    const float* W_do  = (const float*)d_in[21];
    const float* b_do  = (const float*)d_in[22];
    const float* W_f1  = (const float*)d_in[23];
    const float* b_f1  = (const float*)d_in[24];
    const float* W_f2  = (const float*)d_in[25];
    const float* b_f2  = (const float*)d_in[26];
    const float* W_bo  = (const float*)d_in[27];
    const float* b_bo  = (const float*)d_in[28];
    float* out = (float*)d_out;

    int E = in_sizes[2] / 16;
    int nblocks = (E + 127) / 128;
    size_t Epad = (size_t)nblocks * 128;
    size_t nodeElems = (size_t)in_sizes[0];
    size_t wsNeedSmall = ((size_t)WS_ELEMS + nodeElems) * 2;
    size_t wsNeedBig = ((size_t)WS_ELEMS + nodeElems + Epad * 128 + Epad * 256) * 2 + Epad * 4;

    if (ws_size >= wsNeedBig) {
        uint16_t* ws16  = (uint16_t*)d_ws;
        uint16_t* nbf_g = ws16 + WS_ELEMS;
        uint16_t* e3buf = nbf_g + nodeElems;
        uint16_t* hbuf  = e3buf + Epad * 128;
        float*    dpbuf = (float*)(hbuf + Epad * 256);
        prep_w<<<dim3((WS_ELEMS + 255) / 256), dim3(256), 0, stream>>>(
            W_be1, W_be2, W_be3, W_d1, W_d2, W_f1, W_f2, ws16);
        prep_n<<<dim3((int)((nodeElems + 255) / 256)), dim3(256), 0, stream>>>(
            node_emb, nbf_g, (int)nodeElems);
        k_be<<<dim3(nblocks), dim3(512), 0, stream>>>(
            edge_attr, b_be1, g_be1, bb_be1, b_be2, g_be2, bb_be2,
            b_be3, g_be3, bb_be3, ws16, e3buf, E);
        k_d1<<<dim3(nblocks), dim3(512), 0, stream>>>(dual_emb, b_d1, ws16, hbuf, E);
        k_d2<<<dim3(nblocks), dim3(512), 0, stream>>>(b_d2, W_do, b_do, ws16, hbuf, dpbuf, E);
        k_f1<<<dim3(nblocks), dim3(512), 0, stream>>>(
            edge_index, logits, W_f1, b_f1, ws16, nbf_g, e3buf, dpbuf, hbuf, E);
        k_f2<<<dim3(nblocks), dim3(512), 0, stream>>>(b_f2, W_bo, b_bo, ws16, hbuf, out, E);
    } else if (ws_size >= wsNeedSmall) {
        uint16_t* ws16 = (uint16_t*)d_ws;
        prep_w<<<dim3((WS_ELEMS + 255) / 256), dim3(256), 0, stream>>>(
            W_be1, W_be2, W_be3, W_d1, W_d2, W_f1, W_f2, ws16);
        prep_n<<<dim3((int)((nodeElems + 255) / 256)), dim3(256), 0, stream>>>(
            node_emb, ws16 + WS_ELEMS, (int)nodeElems);
        bond_fast_kernel<<<dim3(nblocks), dim3(512), 0, stream>>>(
            edge_index, edge_attr, dual_emb, logits,
            b_be1, g_be1, bb_be1,
            b_be2, g_be2, bb_be2,
            b_be3, g_be3, bb_be3,
            b_d1, b_d2, W_do, b_do,
            W_f1, b_f1, b_f2, W_bo, b_bo,
            ws16, out, E);
    } else {
        bond_fused_kernel<<<dim3(nblocks), dim3(512), 0, stream>>>(
            node_emb, edge_index, edge_attr, dual_emb, logits,
            W_be1, b_be1, g_be1, bb_be1,
            W_be2, b_be2, g_be2, bb_be2,
            W_be3, b_be3, g_be3, bb_be3,
            W_d1, b_d1, W_d2, b_d2, W_do, b_do,
            W_f1, b_f1, W_f2, b_f2, W_bo, b_bo,
            out, E);
    }
}